// Round 16
// baseline (367.503 us; speedup 1.0000x reference)
//
#include <hip/hip_runtime.h>
#include <hip/hip_bf16.h>

#define N_NODES 50000
#define NPAD 50048    // 782 blocks x 64 rows for the fused gather+MLP (R6 structure)
#define KCAP 96       // dense per-row capacity; P(deg > 96 | mean 32) ~ 1e-15
#define CSTRIDE 16    // 16 ints per row: w0..w3 counters live in ONE 64B line
#define NXCD 8        // row windows = XCDs: bucket b consumed only by blocks b mod 8
#define WIN8 6250     // rows per XCD window
#define NW 4          // column windows (sort granularity for gather phase coherence)
#define CWIN 12500    // columns per window
#define KW 40         // bucket capacity per (row, colwindow); P(Poisson(8) > 40) ~ 1e-16
#define RSTRIDE (NW * KW)   // 160 entries per row in windowed colb
#define SCAP 256      // LDS stage capacity per row-window bucket in bin_edges

typedef short v8s __attribute__((ext_vector_type(8)));
typedef unsigned short v8us __attribute__((ext_vector_type(8)));
typedef float v4f __attribute__((ext_vector_type(4)));

// ---------------- helpers ----------------

__device__ __forceinline__ unsigned short f2bf_rne(float f) {
    unsigned int u = __float_as_uint(f);
    u += 0x7FFF + ((u >> 16) & 1);      // round-to-nearest-even
    return (unsigned short)(u >> 16);
}
__device__ __forceinline__ float bflo(unsigned int u) {
    return __uint_as_float(u << 16);
}
__device__ __forceinline__ float bfhi(unsigned int u) {
    return __uint_as_float(u & 0xffff0000u);
}
__device__ __forceinline__ unsigned int pk(float lo, float hi) {
    return (unsigned int)f2bf_rne(lo) | ((unsigned int)f2bf_rne(hi) << 16);
}
__device__ __forceinline__ void acc8(float* acc, uint4 q) {
    acc[0] += bflo(q.x); acc[1] += bfhi(q.x);
    acc[2] += bflo(q.y); acc[3] += bfhi(q.y);
    acc[4] += bflo(q.z); acc[5] += bfhi(q.z);
    acc[6] += bflo(q.w); acc[7] += bfhi(q.w);
}

// ---------------- prep: zero counters + transpose/cast weights ----------------
// W0t[n][k] = bf16(W0[k][n]) (128x128); W1t[n][k] = bf16(W1[k][n]) (64x128)
__global__ void prep(const float* __restrict__ W0, const float* __restrict__ W1,
                     int* __restrict__ cnt, int* __restrict__ bktCnt,
                     unsigned short* __restrict__ W0t, unsigned short* __restrict__ W1t) {
    int i = blockIdx.x * blockDim.x + threadIdx.x;
    if (i < 128) bktCnt[i] = 0;          // 8 bucket counters, 64B-strided
    if (i < N_NODES * CSTRIDE) { cnt[i] = 0; return; }
    int j = i - N_NODES * CSTRIDE;
    if (j < 2048) {
        int n = j >> 4, kc = j & 15;
        unsigned short tmp[8];
#pragma unroll
        for (int q = 0; q < 8; ++q) tmp[q] = f2bf_rne(W0[(kc * 8 + q) * 128 + n]);
        *(uint4*)(W0t + (size_t)n * 128 + kc * 8) = *(uint4*)tmp;
    } else if (j < 3072) {
        int jj = j - 2048;
        int n = jj >> 4, kc = jj & 15;
        unsigned short tmp[8];
#pragma unroll
        for (int q = 0; q < 8; ++q) tmp[q] = f2bf_rne(W1[(kc * 8 + q) * 64 + n]);
        *(uint4*)(W1t + (size_t)n * 128 + kc * 8) = *(uint4*)tmp;
    }
}

// ---------------- build phase A: bin edges by row-window, append-only ----------------
// R18: the R14 counters (build WRITE_SIZE 80 MB for ~19 MB dirty at 73% occ, 8%
// VALU) point to CAPACITY EVICTION: every XCD streamed the full 6.4 MB edge
// list through its 4 MB L2, evicting the dirty colb/cnt window ~4x. Phase A
// does ONE edge scan, staging (row,col) pairs in LDS per row-window bucket,
// then appends contiguous chunks to global buckets via one atomic reservation
// per (block, bucket). Contiguous full-line writes -> no RMW amplification.
__global__ void bin_edges(const int* __restrict__ src, const int* __restrict__ dst,
                          unsigned int* __restrict__ bkt, int* __restrict__ bktCnt,
                          int nEdges, int bcap) {
    __shared__ unsigned int stage[NXCD][SCAP];
    __shared__ int scnt[NXCD];
    __shared__ int sbase[NXCD];
    int tid = threadIdx.x;
    if (tid < NXCD) scnt[tid] = 0;
    __syncthreads();
    int e = blockIdx.x * blockDim.x + tid;
    if (e < nEdges) {
        int s = src[e], d = dst[e];
        int ws = s / WIN8, wd = d / WIN8;
        int p0 = atomicAdd(&scnt[ws], 1);
        stage[ws][p0] = ((unsigned int)s << 16) | (unsigned short)d;   // row s gets col d
        int p1 = atomicAdd(&scnt[wd], 1);
        stage[wd][p1] = ((unsigned int)d << 16) | (unsigned short)s;   // row d gets col s
    }
    __syncthreads();
    if (tid < NXCD) sbase[tid] = atomicAdd(&bktCnt[tid * 16], scnt[tid]);
    __syncthreads();
#pragma unroll
    for (int b = 0; b < NXCD; ++b) {
        int n = scnt[b], base = sbase[b];
        for (int j = tid; j < n; j += 256)
            bkt[(size_t)b * bcap + base + j] = stage[b][j];
    }
}

// ---------------- build phase B: scatter bins -> windowed bucket-CSR ----------------
// Bucket b is consumed ONLY by blocks with blockIdx&7==b (round-robin XCD
// heuristic): per XCD the pair stream is ~0.8 MB and the dirty colb/cnt
// window ~2.4 MB -> both coexist in the 4 MB XCD L2; dirty lines written once.
// Column-window bucketing (wd = col/CWIN) preserved for the gather sort.
__global__ void build_from_bins(const unsigned int* __restrict__ bkt,
                                const int* __restrict__ bktCnt,
                                int* __restrict__ cnt, unsigned short* __restrict__ colb,
                                int bcap) {
    int b = blockIdx.x & (NXCD - 1);
    int i = (blockIdx.x >> 3) * blockDim.x + threadIdx.x;
    if (i >= bktCnt[b * 16]) return;
    unsigned int pr = bkt[(size_t)b * bcap + i];
    int r = (int)(pr >> 16), c = (int)(pr & 0xFFFFu);
    int wd = c / CWIN;
    int q = atomicAdd(&cnt[(r << 4) + wd], 1);
    colb[(size_t)r * RSTRIDE + wd * KW + q] = (unsigned short)c;
}

// ---------------- compact windowed colb -> dense window-sorted list ----------------
// R17: one wave per row concatenates the 4 window segments into colb_d[r*96..].
// Dense list is window-sorted, so the R6-style long gather loop walks columns
// in ascending-window order: concurrent waves stay in a moving ~3 MB band
// (R10 evidence: window-ordering alone cut gather FETCH 160->125 MB).
__global__ void compact_colb(const int* __restrict__ cnt,
                             const unsigned short* __restrict__ colb_w,
                             unsigned short* __restrict__ colb_d) {
    int wave = (int)((blockIdx.x * (unsigned)blockDim.x + threadIdx.x) >> 6);
    if (wave >= N_NODES) return;
    int lane = threadIdx.x & 63;
    int r = wave;
    int4 c4 = *(const int4*)(cnt + (r << 4));
    int cn[4] = {c4.x, c4.y, c4.z, c4.w};
    int off[4] = {0, c4.x, c4.x + c4.y, c4.x + c4.y + c4.z};
    const unsigned short* srcb = colb_w + (size_t)r * RSTRIDE;
    unsigned short* dstb = colb_d + (size_t)r * KCAP;
#pragma unroll
    for (int w = 0; w < 4; ++w) {
        for (int j = lane; j < cn[w]; j += 64)
            dstb[off[w] + j] = srcb[w * KW + j];
    }
}

// ---------------- bf16 conversion (pre-scaled by rsqrt(deg)) ----------------

__global__ void convert_scale_bf16(const float* __restrict__ x, const int* __restrict__ cnt,
                                   unsigned short* __restrict__ xb) {
    long i = (long)blockIdx.x * blockDim.x + threadIdx.x;
    if (i >= (long)N_NODES * 32) return;
    int r = (int)(i >> 5);
    int4 c4 = *(const int4*)(cnt + (r << 4));
    float s = rsqrtf((float)(c4.x + c4.y + c4.z + c4.w) + 1.0f);
    float4 v = ((const float4*)x)[i];
    ushort4 o;
    o.x = f2bf_rne(v.x * s); o.y = f2bf_rne(v.y * s);
    o.z = f2bf_rne(v.z * s); o.w = f2bf_rne(v.w * s);
    ((ushort4*)xb)[i] = o;
}

// ---------------- fused gather(F=128) + MFMA MLP -----------------------------
// R17 gather path unchanged in R18 (so next counters adjudicate it): EXACT R6
// structure (71 us best: occ (256,4), 4 rows/group-iter, 8-deep pipelined loop)
// on the dense window-sorted list. A-frag: A[m=lane&15][k=quad*8+j] (m120);
// C/D col=lane&15,row=quad*4+reg (m89). No __syncthreads (R12 pattern).
__global__ __launch_bounds__(256, 4)
void gather_mlp(const int* __restrict__ cnt,
                const unsigned short* __restrict__ colb,
                const unsigned short* __restrict__ xb,
                const unsigned short* __restrict__ W0t,
                const unsigned short* __restrict__ W1t,
                unsigned short* __restrict__ b16) {
    __shared__ __align__(16) unsigned short Al[4][16 * 136];  // gathered y1 tiles
    __shared__ __align__(16) unsigned short Hl[4][16 * 136];  // hidden tiles
    int t = threadIdx.x;
    int w = t >> 6, lane = t & 63;
    int g = lane >> 4, l = lane & 15;      // group / lane-in-group
    int tilebase = blockIdx.x * 64 + w * 16;
    unsigned short* A = &Al[w][0];
    unsigned short* H = &Hl[w][0];

    // ---- gather phase: group g handles rows tilebase + g + {0,4,8,12}
#pragma unroll
    for (int it = 0; it < 4; ++it) {
        int rr = g + it * 4;
        int r = tilebase + rr;
        float acc[8];
#pragma unroll
        for (int i = 0; i < 8; ++i) acc[i] = 0.f;
        float dr = 0.f;
        if (r < N_NODES) {
            int4 c4 = *(const int4*)(cnt + (r << 4));
            int cn = c4.x + c4.y + c4.z + c4.w;
            const unsigned short* cb = colb + (size_t)r * KCAP;
            int j = 0;
            // 8-deep: one ushort8 index load, 8 dwordx4 row loads in flight
            for (; j + 7 < cn; j += 8) {
                v8us ci = *(const v8us*)(cb + j);
                uint4 q[8];
#pragma unroll
                for (int u = 0; u < 8; ++u)
                    q[u] = ((const uint4*)(xb + (size_t)ci[u] * 128))[l];
#pragma unroll
                for (int u = 0; u < 8; ++u) acc8(acc, q[u]);
            }
            // 4-deep tail
            for (; j + 3 < cn; j += 4) {
                int c0 = cb[j], c1 = cb[j + 1], c2 = cb[j + 2], c3 = cb[j + 3];
                uint4 q0 = ((const uint4*)(xb + (size_t)c0 * 128))[l];
                uint4 q1 = ((const uint4*)(xb + (size_t)c1 * 128))[l];
                uint4 q2 = ((const uint4*)(xb + (size_t)c2 * 128))[l];
                uint4 q3 = ((const uint4*)(xb + (size_t)c3 * 128))[l];
                acc8(acc, q0); acc8(acc, q1); acc8(acc, q2); acc8(acc, q3);
            }
            for (; j < cn; ++j) {
                int c0 = cb[j];
                uint4 q0 = ((const uint4*)(xb + (size_t)c0 * 128))[l];
                acc8(acc, q0);
            }
            // self term
            uint4 qs = ((const uint4*)(xb + (size_t)r * 128))[l];
            acc8(acc, qs);
            dr = rsqrtf((float)cn + 1.0f);
        }
        uint4 o;
        o.x = pk(dr * acc[0], dr * acc[1]);
        o.y = pk(dr * acc[2], dr * acc[3]);
        o.z = pk(dr * acc[4], dr * acc[5]);
        o.w = pk(dr * acc[6], dr * acc[7]);
        *(uint4*)(A + rr * 136 + l * 8) = o;
    }

    // ---- MLP phase (per-wave 16-row tile) ----
    int quad = g, lm = l;
    v8s af[4];
#pragma unroll
    for (int ks = 0; ks < 4; ++ks)
        af[ks] = *(const v8s*)(A + lm * 136 + ks * 32 + quad * 8);

    // phase 1: H(16x128) = relu(A @ W0)
#pragma unroll
    for (int n0 = 0; n0 < 8; ++n0) {
        v4f acc = {0.f, 0.f, 0.f, 0.f};
        const unsigned short* wrow = W0t + (size_t)(n0 * 16 + lm) * 128 + quad * 8;
#pragma unroll
        for (int ks = 0; ks < 4; ++ks) {
            v8s bf = *(const v8s*)(wrow + ks * 32);
            acc = __builtin_amdgcn_mfma_f32_16x16x32_bf16(af[ks], bf, acc, 0, 0, 0);
        }
#pragma unroll
        for (int i = 0; i < 4; ++i)
            H[(quad * 4 + i) * 136 + n0 * 16 + lm] = f2bf_rne(fmaxf(acc[i], 0.f));
    }

    // phase 2: b(16x64) = H @ W1, scale by rsqrt(deg), store bf16
    v8s hf[4];
#pragma unroll
    for (int ks = 0; ks < 4; ++ks)
        hf[ks] = *(const v8s*)(H + lm * 136 + ks * 32 + quad * 8);
    float sc[4];
#pragma unroll
    for (int i = 0; i < 4; ++i) {
        int r = tilebase + quad * 4 + i;
        if (r < N_NODES) {
            int4 c4 = *(const int4*)(cnt + (r << 4));
            sc[i] = rsqrtf((float)(c4.x + c4.y + c4.z + c4.w) + 1.0f);
        } else sc[i] = 0.f;
    }
#pragma unroll
    for (int n0 = 0; n0 < 4; ++n0) {
        v4f acc = {0.f, 0.f, 0.f, 0.f};
        const unsigned short* wrow = W1t + (size_t)(n0 * 16 + lm) * 128 + quad * 8;
#pragma unroll
        for (int ks = 0; ks < 4; ++ks) {
            v8s bf = *(const v8s*)(wrow + ks * 32);
            acc = __builtin_amdgcn_mfma_f32_16x16x32_bf16(hf[ks], bf, acc, 0, 0, 0);
        }
#pragma unroll
        for (int i = 0; i < 4; ++i) {
            int r = tilebase + quad * 4 + i;
            if (r < N_NODES)
                b16[(size_t)r * 64 + n0 * 16 + lm] = f2bf_rne(acc[i] * sc[i]);
        }
    }
}

// ---------------- gather SpMM, F=64, bf16 pre-scaled input ----------------
// R17: EXACT R6 structure (occ (256,4), 4-deep) on the dense window-sorted list.
__global__ __launch_bounds__(256, 4)
void gather_spmm64_bf(const int* __restrict__ cnt,
                      const unsigned short* __restrict__ colb,
                      const unsigned short* __restrict__ hb,
                      float* __restrict__ y) {
    int wave = (int)((blockIdx.x * (unsigned)blockDim.x + threadIdx.x) >> 6);
    if (wave >= N_NODES) return;
    int lane = threadIdx.x & 63;
    int g = lane >> 3;   // group 0..7
    int l = lane & 7;    // covers feats [l*8, l*8+8)
    int r = wave;
    int4 c4 = *(const int4*)(cnt + (r << 4));
    int cn = c4.x + c4.y + c4.z + c4.w;
    const unsigned short* cb = colb + (size_t)r * KCAP;
    float acc[8];
#pragma unroll
    for (int i = 0; i < 8; ++i) acc[i] = 0.f;

    int j = g;
    for (; j + 24 < cn; j += 32) {
        int c0 = cb[j], c1 = cb[j + 8], c2 = cb[j + 16], c3 = cb[j + 24];
        uint4 q0 = ((const uint4*)(hb + (size_t)c0 * 64))[l];
        uint4 q1 = ((const uint4*)(hb + (size_t)c1 * 64))[l];
        uint4 q2 = ((const uint4*)(hb + (size_t)c2 * 64))[l];
        uint4 q3 = ((const uint4*)(hb + (size_t)c3 * 64))[l];
        acc8(acc, q0); acc8(acc, q1); acc8(acc, q2); acc8(acc, q3);
    }
    for (; j + 8 < cn; j += 16) {
        int c0 = cb[j];
        int c1 = cb[j + 8];
        uint4 q0 = ((const uint4*)(hb + (size_t)c0 * 64))[l];
        uint4 q1 = ((const uint4*)(hb + (size_t)c1 * 64))[l];
        acc8(acc, q0); acc8(acc, q1);
    }
    if (j < cn) {
        int c0 = cb[j];
        uint4 q0 = ((const uint4*)(hb + (size_t)c0 * 64))[l];
        acc8(acc, q0);
    }
    if (g == 0) {  // self term
        uint4 q = ((const uint4*)(hb + (size_t)r * 64))[l];
        acc8(acc, q);
    }
#pragma unroll
    for (int i = 0; i < 8; ++i) {
        acc[i] += __shfl_xor(acc[i], 8);
        acc[i] += __shfl_xor(acc[i], 16);
        acc[i] += __shfl_xor(acc[i], 32);
    }
    if (g == 0) {
        float dr = rsqrtf((float)cn + 1.0f);
        float4 o0 = make_float4(dr * acc[0], dr * acc[1], dr * acc[2], dr * acc[3]);
        float4 o1 = make_float4(dr * acc[4], dr * acc[5], dr * acc[6], dr * acc[7]);
        *(float4*)(y + (size_t)r * 64 + l * 8)     = o0;
        *(float4*)(y + (size_t)r * 64 + l * 8 + 4) = o1;
    }
}

// ---------------- launch ----------------

extern "C" void kernel_launch(void* const* d_in, const int* in_sizes, int n_in,
                              void* d_out, int out_size, void* d_ws, size_t ws_size,
                              hipStream_t stream) {
    const float* x  = (const float*)d_in[0];
    const float* W0 = (const float*)d_in[1];
    const float* W1 = (const float*)d_in[2];
    const int* edge = (const int*)d_in[3];
    const int E = in_sizes[3] / 2;
    const int N = N_NODES;
    const int* src = edge;
    const int* dst = edge + E;

    // per-bucket pair capacity: mean 2E/8 + 30% slack
    const int bcap = (int)(((2LL * E) / NXCD) * 13 / 10 + 1024);

    auto align256 = [](size_t v) { return (v + 255) & ~(size_t)255; };
    char* ws = (char*)d_ws;
    size_t off = 0;
    int* cnt = (int*)(ws + off);       off += align256((size_t)N * CSTRIDE * 4);   // 3.2 MB
    int* bktCnt = (int*)(ws + off);    off += align256(128 * 4);                   // 512 B
    unsigned int* bkt = (unsigned int*)(ws + off);
    off += align256((size_t)NXCD * bcap * 4);                                      // ~8.4 MB
    unsigned short* colb_w = (unsigned short*)(ws + off);
    off += align256((size_t)N * RSTRIDE * 2);                                      // 16 MB (windowed)
    unsigned short* colb_d = (unsigned short*)(ws + off);
    off += align256((size_t)N * KCAP * 2);                                         // 9.6 MB (dense sorted)
    unsigned short* xb16 = (unsigned short*)(ws + off);
    off += align256((size_t)N * 128 * 2);                                          // 12.8 MB
    unsigned short* b16 = (unsigned short*)(ws + off);
    off += align256((size_t)N * 64 * 2);                                           // 6.4 MB
    unsigned short* W0t = (unsigned short*)(ws + off); off += align256(128 * 128 * 2);
    unsigned short* W1t = (unsigned short*)(ws + off); off += align256(64 * 128 * 2);
    // total ~56.6 MB

    float* out = (float*)d_out;

    // prep: zero counters + transpose/cast weights (one launch)
    prep<<<(N * CSTRIDE + 3072 + 255) / 256, 256, 0, stream>>>(W0, W1, cnt, bktCnt, W0t, W1t);

    // build phase A: single edge scan -> 8 row-window pair buckets (append-only)
    bin_edges<<<(E + 255) / 256, 256, 0, stream>>>(src, dst, bkt, bktCnt, E, bcap);

    // build phase B: XCD-pinned scatter of each bucket into windowed bucket-CSR
    const int chunksB = (bcap + 255) / 256;
    build_from_bins<<<chunksB * NXCD, 256, 0, stream>>>(bkt, bktCnt, cnt, colb_w, bcap);

    // compact windowed buckets -> dense window-sorted per-row lists
    compact_colb<<<(N * 64 + 255) / 256, 256, 0, stream>>>(cnt, colb_w, colb_d);

    // x -> bf16, pre-scaled by rsqrt(deg)
    long n4 = (long)N * 32;
    convert_scale_bf16<<<(int)((n4 + 255) / 256), 256, 0, stream>>>(x, cnt, xb16);

    // fused: gather y1 tile -> MFMA MLP -> b16 (R6 structure, sorted dense list)
    gather_mlp<<<NPAD / 64, 256, 0, stream>>>(cnt, colb_d, xb16, W0t, W1t, b16);

    // layer 2 gather: out = Â b16 (R6 structure, sorted dense list)
    const int spmm_blocks = (N * 64 + 255) / 256;
    gather_spmm64_bf<<<spmm_blocks, 256, 0, stream>>>(cnt, colb_d, b16, out);
}

// Round 17
// 259.182 us; speedup vs baseline: 1.4179x; 1.4179x over previous
//
#include <hip/hip_runtime.h>
#include <hip/hip_bf16.h>

#define N_NODES 50000
#define NPAD 50048    // 782 blocks x 64 rows for the fused gather+MLP (R6 structure)
#define KCAP 96       // dense per-row capacity; P(deg > 96 | mean 32) ~ 1e-15
#define CSTRIDE 16    // 16 ints per row: w0..w3 counters live in ONE 64B line
#define NW 4          // column windows (sort granularity for gather phase coherence)
#define CWIN 12500    // columns per window
#define NBKT 256      // row buckets in build; one block per bucket in phase B
#define RPB 196       // rows per bucket (196*256 = 50176 >= N)
#define PCAP 32       // pair slots per (bucket, phase-A block); Binomial(2048,1/256) mean 8, 32~11sigma
#define EPB 1024      // edges per phase-A block
#define NBLKA_MAX 800 // cap for lcnt LDS array (E<=819200)

typedef short v8s __attribute__((ext_vector_type(8)));
typedef unsigned short v8us __attribute__((ext_vector_type(8)));
typedef float v4f __attribute__((ext_vector_type(4)));

// ---------------- helpers ----------------

__device__ __forceinline__ unsigned short f2bf_rne(float f) {
    unsigned int u = __float_as_uint(f);
    u += 0x7FFF + ((u >> 16) & 1);      // round-to-nearest-even
    return (unsigned short)(u >> 16);
}
__device__ __forceinline__ float bflo(unsigned int u) {
    return __uint_as_float(u << 16);
}
__device__ __forceinline__ float bfhi(unsigned int u) {
    return __uint_as_float(u & 0xffff0000u);
}
__device__ __forceinline__ unsigned int pk(float lo, float hi) {
    return (unsigned int)f2bf_rne(lo) | ((unsigned int)f2bf_rne(hi) << 16);
}
__device__ __forceinline__ void acc8(float* acc, uint4 q) {
    acc[0] += bflo(q.x); acc[1] += bfhi(q.x);
    acc[2] += bflo(q.y); acc[3] += bfhi(q.y);
    acc[4] += bflo(q.z); acc[5] += bfhi(q.z);
    acc[6] += bflo(q.w); acc[7] += bfhi(q.w);
}

// ---------------- prep: transpose/cast weights only ----------------
// R19: cnt zeroing dropped — build_sorted fully writes the int4 of every row.
// W0t[n][k] = bf16(W0[k][n]) (128x128); W1t[n][k] = bf16(W1[k][n]) (64x128)
__global__ void prep(const float* __restrict__ W0, const float* __restrict__ W1,
                     unsigned short* __restrict__ W0t, unsigned short* __restrict__ W1t) {
    int j = blockIdx.x * blockDim.x + threadIdx.x;
    if (j < 2048) {
        int n = j >> 4, kc = j & 15;
        unsigned short tmp[8];
#pragma unroll
        for (int q = 0; q < 8; ++q) tmp[q] = f2bf_rne(W0[(kc * 8 + q) * 128 + n]);
        *(uint4*)(W0t + (size_t)n * 128 + kc * 8) = *(uint4*)tmp;
    } else if (j < 3072) {
        int jj = j - 2048;
        int n = jj >> 4, kc = jj & 15;
        unsigned short tmp[8];
#pragma unroll
        for (int q = 0; q < 8; ++q) tmp[q] = f2bf_rne(W1[(kc * 8 + q) * 64 + n]);
        *(uint4*)(W1t + (size_t)n * 128 + kc * 8) = *(uint4*)tmp;
    }
}

// ---------------- build phase A: deterministic pair binning, ZERO global atomics ----
// R19: WRITE_SIZE was invariant (~73-85 MB) across R3/R14/R18 build variants; the
// invariant is the 1.6M per-pair device-scope atomicAdds — each is a memory-side
// line RMW (cross-XCD visibility), ~1.2M x 64B = the observed write tax + its
// serialization. Phase A removes them: block i owns slot range (bucket, i) in
// bktPairs, so placement is deterministic. LDS staging, then per-bucket flush.
__global__ void bin_pairs(const int* __restrict__ src, const int* __restrict__ dst,
                          unsigned int* __restrict__ bktPairs, int* __restrict__ cntA,
                          int nEdges, int nblkA) {
    __shared__ unsigned int stage[NBKT * PCAP];   // 32 KB
    __shared__ int scnt[NBKT];
    int tid = threadIdx.x;
    for (int i = tid; i < NBKT; i += 256) scnt[i] = 0;
    __syncthreads();
    int e0 = blockIdx.x * EPB;
#pragma unroll
    for (int k = 0; k < EPB / 256; ++k) {
        int e = e0 + k * 256 + tid;
        if (e < nEdges) {
            int s = src[e], d = dst[e];
            int bs = s / RPB, bd = d / RPB;
            int p = atomicAdd(&scnt[bs], 1);                    // LDS atomic (cheap)
            if (p < PCAP) stage[bs * PCAP + p] = ((unsigned int)s << 16) | (unsigned int)d;
            p = atomicAdd(&scnt[bd], 1);
            if (p < PCAP) stage[bd * PCAP + p] = ((unsigned int)d << 16) | (unsigned int)s;
        }
    }
    __syncthreads();
    // flush: thread t owns bucket t
    int n = scnt[tid]; if (n > PCAP) n = PCAP;
    unsigned int* dp = bktPairs + ((size_t)tid * nblkA + blockIdx.x) * PCAP;
    for (int j = 0; j < n; ++j) dp[j] = stage[tid * PCAP + j];
    cntA[(size_t)tid * nblkA + blockIdx.x] = n;
}

// ---------------- build phase B: single-writer dense window-sorted CSR --------
// One block per bucket (196 rows): LDS histogram of (row, colwindow) -> per-row
// dense prefix -> LDS-offset scatter. ZERO global atomics; colb_d written dense
// and window-sorted directly (compact_colb eliminated). cnt int4 = window counts.
__global__ void build_sorted(const unsigned int* __restrict__ bktPairs,
                             const int* __restrict__ cntA,
                             int* __restrict__ cnt, unsigned short* __restrict__ colb_d,
                             int nblkA) {
    __shared__ int hist[RPB * 4];     // counts, then running dense positions
    __shared__ int lcnt[NBLKA_MAX];
    int tid = threadIdx.x;
    int k = blockIdx.x;
    int lo = k * RPB;
    for (int i = tid; i < nblkA; i += 256) lcnt[i] = cntA[(size_t)k * nblkA + i];
    for (int i = tid; i < RPB * 4; i += 256) hist[i] = 0;
    __syncthreads();
    const unsigned int* bp = bktPairs + (size_t)k * nblkA * PCAP;
    int nslots = nblkA * PCAP;
    // pass 1: histogram (coalesced slot stream)
    for (int s = tid; s < nslots; s += 256) {
        int blk = s >> 5, j = s & (PCAP - 1);
        if (j < lcnt[blk]) {
            unsigned int pr = bp[s];
            int rr = (int)(pr >> 16) - lo;
            int c = (int)(pr & 0xFFFFu);
            atomicAdd(&hist[rr * 4 + c / CWIN], 1);
        }
    }
    __syncthreads();
    // per-row: store cnt int4, convert hist to dense window prefix
    for (int rr = tid; rr < RPB; rr += 256) {
        int r = lo + rr;
        if (r < N_NODES) {
            int h0 = hist[rr * 4], h1 = hist[rr * 4 + 1];
            int h2 = hist[rr * 4 + 2], h3 = hist[rr * 4 + 3];
            *(int4*)(cnt + ((size_t)r << 4)) = make_int4(h0, h1, h2, h3);
            hist[rr * 4] = 0;
            hist[rr * 4 + 1] = h0;
            hist[rr * 4 + 2] = h0 + h1;
            hist[rr * 4 + 3] = h0 + h1 + h2;
        }
    }
    __syncthreads();
    // pass 2: scatter into dense window-sorted list
    for (int s = tid; s < nslots; s += 256) {
        int blk = s >> 5, j = s & (PCAP - 1);
        if (j < lcnt[blk]) {
            unsigned int pr = bp[s];
            int rr = (int)(pr >> 16) - lo;
            int c = (int)(pr & 0xFFFFu);
            int pos = atomicAdd(&hist[rr * 4 + c / CWIN], 1);
            if (pos < KCAP) colb_d[(size_t)(lo + rr) * KCAP + pos] = (unsigned short)c;
        }
    }
}

// ---------------- bf16 conversion (pre-scaled by rsqrt(deg)) ----------------

__global__ void convert_scale_bf16(const float* __restrict__ x, const int* __restrict__ cnt,
                                   unsigned short* __restrict__ xb) {
    long i = (long)blockIdx.x * blockDim.x + threadIdx.x;
    if (i >= (long)N_NODES * 32) return;
    int r = (int)(i >> 5);
    int4 c4 = *(const int4*)(cnt + (r << 4));
    float s = rsqrtf((float)(c4.x + c4.y + c4.z + c4.w) + 1.0f);
    float4 v = ((const float4*)x)[i];
    ushort4 o;
    o.x = f2bf_rne(v.x * s); o.y = f2bf_rne(v.y * s);
    o.z = f2bf_rne(v.z * s); o.w = f2bf_rne(v.w * s);
    ((ushort4*)xb)[i] = o;
}

// ---------------- fused gather(F=128) + MFMA MLP -----------------------------
// R17 gather path unchanged (adjudicated by this round's counters): EXACT R6
// structure (71 us best: occ (256,4), 4 rows/group-iter, 8-deep pipelined loop)
// on the dense window-sorted list. A-frag: A[m=lane&15][k=quad*8+j] (m120);
// C/D col=lane&15,row=quad*4+reg (m89). No __syncthreads (R12 pattern).
__global__ __launch_bounds__(256, 4)
void gather_mlp(const int* __restrict__ cnt,
                const unsigned short* __restrict__ colb,
                const unsigned short* __restrict__ xb,
                const unsigned short* __restrict__ W0t,
                const unsigned short* __restrict__ W1t,
                unsigned short* __restrict__ b16) {
    __shared__ __align__(16) unsigned short Al[4][16 * 136];  // gathered y1 tiles
    __shared__ __align__(16) unsigned short Hl[4][16 * 136];  // hidden tiles
    int t = threadIdx.x;
    int w = t >> 6, lane = t & 63;
    int g = lane >> 4, l = lane & 15;      // group / lane-in-group
    int tilebase = blockIdx.x * 64 + w * 16;
    unsigned short* A = &Al[w][0];
    unsigned short* H = &Hl[w][0];

    // ---- gather phase: group g handles rows tilebase + g + {0,4,8,12}
#pragma unroll
    for (int it = 0; it < 4; ++it) {
        int rr = g + it * 4;
        int r = tilebase + rr;
        float acc[8];
#pragma unroll
        for (int i = 0; i < 8; ++i) acc[i] = 0.f;
        float dr = 0.f;
        if (r < N_NODES) {
            int4 c4 = *(const int4*)(cnt + (r << 4));
            int cn = c4.x + c4.y + c4.z + c4.w;
            const unsigned short* cb = colb + (size_t)r * KCAP;
            int j = 0;
            // 8-deep: one ushort8 index load, 8 dwordx4 row loads in flight
            for (; j + 7 < cn; j += 8) {
                v8us ci = *(const v8us*)(cb + j);
                uint4 q[8];
#pragma unroll
                for (int u = 0; u < 8; ++u)
                    q[u] = ((const uint4*)(xb + (size_t)ci[u] * 128))[l];
#pragma unroll
                for (int u = 0; u < 8; ++u) acc8(acc, q[u]);
            }
            // 4-deep tail
            for (; j + 3 < cn; j += 4) {
                int c0 = cb[j], c1 = cb[j + 1], c2 = cb[j + 2], c3 = cb[j + 3];
                uint4 q0 = ((const uint4*)(xb + (size_t)c0 * 128))[l];
                uint4 q1 = ((const uint4*)(xb + (size_t)c1 * 128))[l];
                uint4 q2 = ((const uint4*)(xb + (size_t)c2 * 128))[l];
                uint4 q3 = ((const uint4*)(xb + (size_t)c3 * 128))[l];
                acc8(acc, q0); acc8(acc, q1); acc8(acc, q2); acc8(acc, q3);
            }
            for (; j < cn; ++j) {
                int c0 = cb[j];
                uint4 q0 = ((const uint4*)(xb + (size_t)c0 * 128))[l];
                acc8(acc, q0);
            }
            // self term
            uint4 qs = ((const uint4*)(xb + (size_t)r * 128))[l];
            acc8(acc, qs);
            dr = rsqrtf((float)cn + 1.0f);
        }
        uint4 o;
        o.x = pk(dr * acc[0], dr * acc[1]);
        o.y = pk(dr * acc[2], dr * acc[3]);
        o.z = pk(dr * acc[4], dr * acc[5]);
        o.w = pk(dr * acc[6], dr * acc[7]);
        *(uint4*)(A + rr * 136 + l * 8) = o;
    }

    // ---- MLP phase (per-wave 16-row tile) ----
    int quad = g, lm = l;
    v8s af[4];
#pragma unroll
    for (int ks = 0; ks < 4; ++ks)
        af[ks] = *(const v8s*)(A + lm * 136 + ks * 32 + quad * 8);

    // phase 1: H(16x128) = relu(A @ W0)
#pragma unroll
    for (int n0 = 0; n0 < 8; ++n0) {
        v4f acc = {0.f, 0.f, 0.f, 0.f};
        const unsigned short* wrow = W0t + (size_t)(n0 * 16 + lm) * 128 + quad * 8;
#pragma unroll
        for (int ks = 0; ks < 4; ++ks) {
            v8s bf = *(const v8s*)(wrow + ks * 32);
            acc = __builtin_amdgcn_mfma_f32_16x16x32_bf16(af[ks], bf, acc, 0, 0, 0);
        }
#pragma unroll
        for (int i = 0; i < 4; ++i)
            H[(quad * 4 + i) * 136 + n0 * 16 + lm] = f2bf_rne(fmaxf(acc[i], 0.f));
    }

    // phase 2: b(16x64) = H @ W1, scale by rsqrt(deg), store bf16
    v8s hf[4];
#pragma unroll
    for (int ks = 0; ks < 4; ++ks)
        hf[ks] = *(const v8s*)(H + lm * 136 + ks * 32 + quad * 8);
    float sc[4];
#pragma unroll
    for (int i = 0; i < 4; ++i) {
        int r = tilebase + quad * 4 + i;
        if (r < N_NODES) {
            int4 c4 = *(const int4*)(cnt + (r << 4));
            sc[i] = rsqrtf((float)(c4.x + c4.y + c4.z + c4.w) + 1.0f);
        } else sc[i] = 0.f;
    }
#pragma unroll
    for (int n0 = 0; n0 < 4; ++n0) {
        v4f acc = {0.f, 0.f, 0.f, 0.f};
        const unsigned short* wrow = W1t + (size_t)(n0 * 16 + lm) * 128 + quad * 8;
#pragma unroll
        for (int ks = 0; ks < 4; ++ks) {
            v8s bf = *(const v8s*)(wrow + ks * 32);
            acc = __builtin_amdgcn_mfma_f32_16x16x32_bf16(hf[ks], bf, acc, 0, 0, 0);
        }
#pragma unroll
        for (int i = 0; i < 4; ++i) {
            int r = tilebase + quad * 4 + i;
            if (r < N_NODES)
                b16[(size_t)r * 64 + n0 * 16 + lm] = f2bf_rne(acc[i] * sc[i]);
        }
    }
}

// ---------------- gather SpMM, F=64, bf16 pre-scaled input ----------------
// R17: EXACT R6 structure (occ (256,4), 4-deep) on the dense window-sorted list.
__global__ __launch_bounds__(256, 4)
void gather_spmm64_bf(const int* __restrict__ cnt,
                      const unsigned short* __restrict__ colb,
                      const unsigned short* __restrict__ hb,
                      float* __restrict__ y) {
    int wave = (int)((blockIdx.x * (unsigned)blockDim.x + threadIdx.x) >> 6);
    if (wave >= N_NODES) return;
    int lane = threadIdx.x & 63;
    int g = lane >> 3;   // group 0..7
    int l = lane & 7;    // covers feats [l*8, l*8+8)
    int r = wave;
    int4 c4 = *(const int4*)(cnt + (r << 4));
    int cn = c4.x + c4.y + c4.z + c4.w;
    const unsigned short* cb = colb + (size_t)r * KCAP;
    float acc[8];
#pragma unroll
    for (int i = 0; i < 8; ++i) acc[i] = 0.f;

    int j = g;
    for (; j + 24 < cn; j += 32) {
        int c0 = cb[j], c1 = cb[j + 8], c2 = cb[j + 16], c3 = cb[j + 24];
        uint4 q0 = ((const uint4*)(hb + (size_t)c0 * 64))[l];
        uint4 q1 = ((const uint4*)(hb + (size_t)c1 * 64))[l];
        uint4 q2 = ((const uint4*)(hb + (size_t)c2 * 64))[l];
        uint4 q3 = ((const uint4*)(hb + (size_t)c3 * 64))[l];
        acc8(acc, q0); acc8(acc, q1); acc8(acc, q2); acc8(acc, q3);
    }
    for (; j + 8 < cn; j += 16) {
        int c0 = cb[j];
        int c1 = cb[j + 8];
        uint4 q0 = ((const uint4*)(hb + (size_t)c0 * 64))[l];
        uint4 q1 = ((const uint4*)(hb + (size_t)c1 * 64))[l];
        acc8(acc, q0); acc8(acc, q1);
    }
    if (j < cn) {
        int c0 = cb[j];
        uint4 q0 = ((const uint4*)(hb + (size_t)c0 * 64))[l];
        acc8(acc, q0);
    }
    if (g == 0) {  // self term
        uint4 q = ((const uint4*)(hb + (size_t)r * 64))[l];
        acc8(acc, q);
    }
#pragma unroll
    for (int i = 0; i < 8; ++i) {
        acc[i] += __shfl_xor(acc[i], 8);
        acc[i] += __shfl_xor(acc[i], 16);
        acc[i] += __shfl_xor(acc[i], 32);
    }
    if (g == 0) {
        float dr = rsqrtf((float)cn + 1.0f);
        float4 o0 = make_float4(dr * acc[0], dr * acc[1], dr * acc[2], dr * acc[3]);
        float4 o1 = make_float4(dr * acc[4], dr * acc[5], dr * acc[6], dr * acc[7]);
        *(float4*)(y + (size_t)r * 64 + l * 8)     = o0;
        *(float4*)(y + (size_t)r * 64 + l * 8 + 4) = o1;
    }
}

// ---------------- launch ----------------

extern "C" void kernel_launch(void* const* d_in, const int* in_sizes, int n_in,
                              void* d_out, int out_size, void* d_ws, size_t ws_size,
                              hipStream_t stream) {
    const float* x  = (const float*)d_in[0];
    const float* W0 = (const float*)d_in[1];
    const float* W1 = (const float*)d_in[2];
    const int* edge = (const int*)d_in[3];
    const int E = in_sizes[3] / 2;
    const int N = N_NODES;
    const int* src = edge;
    const int* dst = edge + E;

    int nblkA = (E + EPB - 1) / EPB;          // 782 for E=800000
    if (nblkA > NBLKA_MAX) nblkA = NBLKA_MAX; // structural cap (E fixed by problem)

    auto align256 = [](size_t v) { return (v + 255) & ~(size_t)255; };
    char* ws = (char*)d_ws;
    size_t off = 0;
    int* cnt = (int*)(ws + off);       off += align256((size_t)N * CSTRIDE * 4);   // 3.2 MB
    int* cntA = (int*)(ws + off);      off += align256((size_t)NBKT * NBLKA_MAX * 4);   // 0.8 MB
    unsigned int* bktPairs = (unsigned int*)(ws + off);
    off += align256((size_t)NBKT * NBLKA_MAX * PCAP * 4);                          // 26.2 MB
    unsigned short* colb_d = (unsigned short*)(ws + off);
    off += align256((size_t)N * KCAP * 2);                                         // 9.6 MB (dense sorted)
    unsigned short* xb16 = (unsigned short*)(ws + off);
    off += align256((size_t)N * 128 * 2);                                          // 12.8 MB
    unsigned short* b16 = (unsigned short*)(ws + off);
    off += align256((size_t)N * 64 * 2);                                           // 6.4 MB
    unsigned short* W0t = (unsigned short*)(ws + off); off += align256(128 * 128 * 2);
    unsigned short* W1t = (unsigned short*)(ws + off); off += align256(64 * 128 * 2);
    // total ~59 MB

    float* out = (float*)d_out;

    // prep: transpose/cast weights (cnt zeroing no longer needed)
    prep<<<(3072 + 255) / 256, 256, 0, stream>>>(W0, W1, W0t, W1t);

    // build phase A: deterministic pair binning (no global atomics)
    bin_pairs<<<nblkA, 256, 0, stream>>>(src, dst, bktPairs, cntA, E, nblkA);

    // build phase B: single-writer dense window-sorted CSR (no global atomics)
    build_sorted<<<NBKT, 256, 0, stream>>>(bktPairs, cntA, cnt, colb_d, nblkA);

    // x -> bf16, pre-scaled by rsqrt(deg)
    long n4 = (long)N * 32;
    convert_scale_bf16<<<(int)((n4 + 255) / 256), 256, 0, stream>>>(x, cnt, xb16);

    // fused: gather y1 tile -> MFMA MLP -> b16 (R6 structure, sorted dense list)
    gather_mlp<<<NPAD / 64, 256, 0, stream>>>(cnt, colb_d, xb16, W0t, W1t, b16);

    // layer 2 gather: out = Â b16 (R6 structure, sorted dense list)
    const int spmm_blocks = (N * 64 + 255) / 256;
    gather_spmm64_bf<<<spmm_blocks, 256, 0, stream>>>(cnt, colb_d, b16, out);
}

// Round 18
// 212.052 us; speedup vs baseline: 1.7331x; 1.2223x over previous
//
#include <hip/hip_runtime.h>
#include <hip/hip_bf16.h>

#define N_NODES 50000
#define NPAD 50048    // 782 blocks x 64 rows for the fused gather+MLP (R6 structure)
#define KCAP 96       // dense per-row capacity; P(deg > 96 | mean 32) ~ 1e-15
#define CSTRIDE 16    // 16 ints per row: w0..w3 counters live in ONE 64B line
#define NW 4          // column windows (sort granularity for gather phase coherence)
#define CWIN 12500    // columns per window
#define NBKT 256      // row buckets in build; one block per bucket in phase B
#define RPB 196       // rows per bucket (196*256 = 50176 >= N)
#define PCAP 32       // pair slots per (bucket, phase-A block); Binomial(2048,1/256) mean 8, 32~11sigma
#define EPB 1024      // edges per phase-A block
#define NBLKA_MAX 800 // cap for lcnt LDS array (E<=819200)
#define TB_B 1024     // R20: phase-B block size 256->1024 (16 waves/CU; occ was 8.7%)

typedef short v8s __attribute__((ext_vector_type(8)));
typedef unsigned short v8us __attribute__((ext_vector_type(8)));
typedef float v4f __attribute__((ext_vector_type(4)));

// ---------------- helpers ----------------

__device__ __forceinline__ unsigned short f2bf_rne(float f) {
    unsigned int u = __float_as_uint(f);
    u += 0x7FFF + ((u >> 16) & 1);      // round-to-nearest-even
    return (unsigned short)(u >> 16);
}
__device__ __forceinline__ float bflo(unsigned int u) {
    return __uint_as_float(u << 16);
}
__device__ __forceinline__ float bfhi(unsigned int u) {
    return __uint_as_float(u & 0xffff0000u);
}
__device__ __forceinline__ unsigned int pk(float lo, float hi) {
    return (unsigned int)f2bf_rne(lo) | ((unsigned int)f2bf_rne(hi) << 16);
}
__device__ __forceinline__ void acc8(float* acc, uint4 q) {
    acc[0] += bflo(q.x); acc[1] += bfhi(q.x);
    acc[2] += bflo(q.y); acc[3] += bfhi(q.y);
    acc[4] += bflo(q.z); acc[5] += bfhi(q.z);
    acc[6] += bflo(q.w); acc[7] += bfhi(q.w);
}

// ---------------- prep: transpose/cast weights only ----------------
// W0t[n][k] = bf16(W0[k][n]) (128x128); W1t[n][k] = bf16(W1[k][n]) (64x128)
__global__ void prep(const float* __restrict__ W0, const float* __restrict__ W1,
                     unsigned short* __restrict__ W0t, unsigned short* __restrict__ W1t) {
    int j = blockIdx.x * blockDim.x + threadIdx.x;
    if (j < 2048) {
        int n = j >> 4, kc = j & 15;
        unsigned short tmp[8];
#pragma unroll
        for (int q = 0; q < 8; ++q) tmp[q] = f2bf_rne(W0[(kc * 8 + q) * 128 + n]);
        *(uint4*)(W0t + (size_t)n * 128 + kc * 8) = *(uint4*)tmp;
    } else if (j < 3072) {
        int jj = j - 2048;
        int n = jj >> 4, kc = jj & 15;
        unsigned short tmp[8];
#pragma unroll
        for (int q = 0; q < 8; ++q) tmp[q] = f2bf_rne(W1[(kc * 8 + q) * 64 + n]);
        *(uint4*)(W1t + (size_t)n * 128 + kc * 8) = *(uint4*)tmp;
    }
}

// ---------------- build phase A: deterministic pair binning, ZERO global atomics ----
// R19 (verified R17 counters: build WRITE 73->6.3 MB): the ~70 MB write tax across
// R3/R14/R18 was the 1.6M device-scope atomicAdds (memory-side line RMW for
// cross-XCD visibility). Phase A: block i owns slot range (bucket, i), placement
// deterministic, LDS staging, per-bucket flush. No global atomics anywhere.
__global__ void bin_pairs(const int* __restrict__ src, const int* __restrict__ dst,
                          unsigned int* __restrict__ bktPairs, int* __restrict__ cntA,
                          int nEdges, int nblkA) {
    __shared__ unsigned int stage[NBKT * PCAP];   // 32 KB
    __shared__ int scnt[NBKT];
    int tid = threadIdx.x;
    for (int i = tid; i < NBKT; i += 256) scnt[i] = 0;
    __syncthreads();
    int e0 = blockIdx.x * EPB;
#pragma unroll
    for (int k = 0; k < EPB / 256; ++k) {
        int e = e0 + k * 256 + tid;
        if (e < nEdges) {
            int s = src[e], d = dst[e];
            int bs = s / RPB, bd = d / RPB;
            int p = atomicAdd(&scnt[bs], 1);                    // LDS atomic (cheap)
            if (p < PCAP) stage[bs * PCAP + p] = ((unsigned int)s << 16) | (unsigned int)d;
            p = atomicAdd(&scnt[bd], 1);
            if (p < PCAP) stage[bd * PCAP + p] = ((unsigned int)d << 16) | (unsigned int)s;
        }
    }
    __syncthreads();
    // flush: thread t owns bucket t
    int n = scnt[tid]; if (n > PCAP) n = PCAP;
    unsigned int* dp = bktPairs + ((size_t)tid * nblkA + blockIdx.x) * PCAP;
    for (int j = 0; j < n; ++j) dp[j] = stage[tid * PCAP + j];
    cntA[(size_t)tid * nblkA + blockIdx.x] = n;
}

// ---------------- build phase B: single-writer dense window-sorted CSR --------
// One block per bucket (196 rows): LDS histogram of (row, colwindow) -> per-row
// dense prefix -> LDS-offset scatter. ZERO global atomics; colb_d written dense
// and window-sorted directly. cnt int4 = window counts.
// R20: block 256->1024 threads. R17 counters: occ 8.7% (1 blk/CU x 4 waves),
// VALU 4.6%, 17 MB at 200 GB/s -> wave-starved latency chain {load, LDS-atomic}.
// 16 waves/CU quadruples in-flight loads; slot scan drops to 24 iters/thread.
__global__ __launch_bounds__(TB_B, 1)
void build_sorted(const unsigned int* __restrict__ bktPairs,
                  const int* __restrict__ cntA,
                  int* __restrict__ cnt, unsigned short* __restrict__ colb_d,
                  int nblkA) {
    __shared__ int hist[RPB * 4];     // counts, then running dense positions
    __shared__ int lcnt[NBLKA_MAX];
    int tid = threadIdx.x;
    int k = blockIdx.x;
    int lo = k * RPB;
    for (int i = tid; i < nblkA; i += TB_B) lcnt[i] = cntA[(size_t)k * nblkA + i];
    for (int i = tid; i < RPB * 4; i += TB_B) hist[i] = 0;
    __syncthreads();
    const unsigned int* bp = bktPairs + (size_t)k * nblkA * PCAP;
    int nslots = nblkA * PCAP;
    // pass 1: histogram (coalesced slot stream)
    for (int s = tid; s < nslots; s += TB_B) {
        int blk = s >> 5, j = s & (PCAP - 1);
        if (j < lcnt[blk]) {
            unsigned int pr = bp[s];
            int rr = (int)(pr >> 16) - lo;
            int c = (int)(pr & 0xFFFFu);
            atomicAdd(&hist[rr * 4 + c / CWIN], 1);
        }
    }
    __syncthreads();
    // per-row: store cnt int4, convert hist to dense window prefix
    for (int rr = tid; rr < RPB; rr += TB_B) {
        int r = lo + rr;
        if (r < N_NODES) {
            int h0 = hist[rr * 4], h1 = hist[rr * 4 + 1];
            int h2 = hist[rr * 4 + 2], h3 = hist[rr * 4 + 3];
            *(int4*)(cnt + ((size_t)r << 4)) = make_int4(h0, h1, h2, h3);
            hist[rr * 4] = 0;
            hist[rr * 4 + 1] = h0;
            hist[rr * 4 + 2] = h0 + h1;
            hist[rr * 4 + 3] = h0 + h1 + h2;
        }
    }
    __syncthreads();
    // pass 2: scatter into dense window-sorted list
    for (int s = tid; s < nslots; s += TB_B) {
        int blk = s >> 5, j = s & (PCAP - 1);
        if (j < lcnt[blk]) {
            unsigned int pr = bp[s];
            int rr = (int)(pr >> 16) - lo;
            int c = (int)(pr & 0xFFFFu);
            int pos = atomicAdd(&hist[rr * 4 + c / CWIN], 1);
            if (pos < KCAP) colb_d[(size_t)(lo + rr) * KCAP + pos] = (unsigned short)c;
        }
    }
}

// ---------------- bf16 conversion (pre-scaled by rsqrt(deg)) ----------------

__global__ void convert_scale_bf16(const float* __restrict__ x, const int* __restrict__ cnt,
                                   unsigned short* __restrict__ xb) {
    long i = (long)blockIdx.x * blockDim.x + threadIdx.x;
    if (i >= (long)N_NODES * 32) return;
    int r = (int)(i >> 5);
    int4 c4 = *(const int4*)(cnt + (r << 4));
    float s = rsqrtf((float)(c4.x + c4.y + c4.z + c4.w) + 1.0f);
    float4 v = ((const float4*)x)[i];
    ushort4 o;
    o.x = f2bf_rne(v.x * s); o.y = f2bf_rne(v.y * s);
    o.z = f2bf_rne(v.z * s); o.w = f2bf_rne(v.w * s);
    ((ushort4*)xb)[i] = o;
}

// ---------------- fused gather(F=128) + MFMA MLP -----------------------------
// R17 gather path unchanged (adjudicated when it tops the table): EXACT R6
// structure (71 us best: occ (256,4), 4 rows/group-iter, 8-deep pipelined loop)
// on the dense window-sorted list. A-frag: A[m=lane&15][k=quad*8+j] (m120);
// C/D col=lane&15,row=quad*4+reg (m89). No __syncthreads (R12 pattern).
__global__ __launch_bounds__(256, 4)
void gather_mlp(const int* __restrict__ cnt,
                const unsigned short* __restrict__ colb,
                const unsigned short* __restrict__ xb,
                const unsigned short* __restrict__ W0t,
                const unsigned short* __restrict__ W1t,
                unsigned short* __restrict__ b16) {
    __shared__ __align__(16) unsigned short Al[4][16 * 136];  // gathered y1 tiles
    __shared__ __align__(16) unsigned short Hl[4][16 * 136];  // hidden tiles
    int t = threadIdx.x;
    int w = t >> 6, lane = t & 63;
    int g = lane >> 4, l = lane & 15;      // group / lane-in-group
    int tilebase = blockIdx.x * 64 + w * 16;
    unsigned short* A = &Al[w][0];
    unsigned short* H = &Hl[w][0];

    // ---- gather phase: group g handles rows tilebase + g + {0,4,8,12}
#pragma unroll
    for (int it = 0; it < 4; ++it) {
        int rr = g + it * 4;
        int r = tilebase + rr;
        float acc[8];
#pragma unroll
        for (int i = 0; i < 8; ++i) acc[i] = 0.f;
        float dr = 0.f;
        if (r < N_NODES) {
            int4 c4 = *(const int4*)(cnt + (r << 4));
            int cn = c4.x + c4.y + c4.z + c4.w;
            const unsigned short* cb = colb + (size_t)r * KCAP;
            int j = 0;
            // 8-deep: one ushort8 index load, 8 dwordx4 row loads in flight
            for (; j + 7 < cn; j += 8) {
                v8us ci = *(const v8us*)(cb + j);
                uint4 q[8];
#pragma unroll
                for (int u = 0; u < 8; ++u)
                    q[u] = ((const uint4*)(xb + (size_t)ci[u] * 128))[l];
#pragma unroll
                for (int u = 0; u < 8; ++u) acc8(acc, q[u]);
            }
            // 4-deep tail
            for (; j + 3 < cn; j += 4) {
                int c0 = cb[j], c1 = cb[j + 1], c2 = cb[j + 2], c3 = cb[j + 3];
                uint4 q0 = ((const uint4*)(xb + (size_t)c0 * 128))[l];
                uint4 q1 = ((const uint4*)(xb + (size_t)c1 * 128))[l];
                uint4 q2 = ((const uint4*)(xb + (size_t)c2 * 128))[l];
                uint4 q3 = ((const uint4*)(xb + (size_t)c3 * 128))[l];
                acc8(acc, q0); acc8(acc, q1); acc8(acc, q2); acc8(acc, q3);
            }
            for (; j < cn; ++j) {
                int c0 = cb[j];
                uint4 q0 = ((const uint4*)(xb + (size_t)c0 * 128))[l];
                acc8(acc, q0);
            }
            // self term
            uint4 qs = ((const uint4*)(xb + (size_t)r * 128))[l];
            acc8(acc, qs);
            dr = rsqrtf((float)cn + 1.0f);
        }
        uint4 o;
        o.x = pk(dr * acc[0], dr * acc[1]);
        o.y = pk(dr * acc[2], dr * acc[3]);
        o.z = pk(dr * acc[4], dr * acc[5]);
        o.w = pk(dr * acc[6], dr * acc[7]);
        *(uint4*)(A + rr * 136 + l * 8) = o;
    }

    // ---- MLP phase (per-wave 16-row tile) ----
    int quad = g, lm = l;
    v8s af[4];
#pragma unroll
    for (int ks = 0; ks < 4; ++ks)
        af[ks] = *(const v8s*)(A + lm * 136 + ks * 32 + quad * 8);

    // phase 1: H(16x128) = relu(A @ W0)
#pragma unroll
    for (int n0 = 0; n0 < 8; ++n0) {
        v4f acc = {0.f, 0.f, 0.f, 0.f};
        const unsigned short* wrow = W0t + (size_t)(n0 * 16 + lm) * 128 + quad * 8;
#pragma unroll
        for (int ks = 0; ks < 4; ++ks) {
            v8s bf = *(const v8s*)(wrow + ks * 32);
            acc = __builtin_amdgcn_mfma_f32_16x16x32_bf16(af[ks], bf, acc, 0, 0, 0);
        }
#pragma unroll
        for (int i = 0; i < 4; ++i)
            H[(quad * 4 + i) * 136 + n0 * 16 + lm] = f2bf_rne(fmaxf(acc[i], 0.f));
    }

    // phase 2: b(16x64) = H @ W1, scale by rsqrt(deg), store bf16
    v8s hf[4];
#pragma unroll
    for (int ks = 0; ks < 4; ++ks)
        hf[ks] = *(const v8s*)(H + lm * 136 + ks * 32 + quad * 8);
    float sc[4];
#pragma unroll
    for (int i = 0; i < 4; ++i) {
        int r = tilebase + quad * 4 + i;
        if (r < N_NODES) {
            int4 c4 = *(const int4*)(cnt + (r << 4));
            sc[i] = rsqrtf((float)(c4.x + c4.y + c4.z + c4.w) + 1.0f);
        } else sc[i] = 0.f;
    }
#pragma unroll
    for (int n0 = 0; n0 < 4; ++n0) {
        v4f acc = {0.f, 0.f, 0.f, 0.f};
        const unsigned short* wrow = W1t + (size_t)(n0 * 16 + lm) * 128 + quad * 8;
#pragma unroll
        for (int ks = 0; ks < 4; ++ks) {
            v8s bf = *(const v8s*)(wrow + ks * 32);
            acc = __builtin_amdgcn_mfma_f32_16x16x32_bf16(hf[ks], bf, acc, 0, 0, 0);
        }
#pragma unroll
        for (int i = 0; i < 4; ++i) {
            int r = tilebase + quad * 4 + i;
            if (r < N_NODES)
                b16[(size_t)r * 64 + n0 * 16 + lm] = f2bf_rne(acc[i] * sc[i]);
        }
    }
}

// ---------------- gather SpMM, F=64, bf16 pre-scaled input ----------------
// R17: EXACT R6 structure (occ (256,4), 4-deep) on the dense window-sorted list.
__global__ __launch_bounds__(256, 4)
void gather_spmm64_bf(const int* __restrict__ cnt,
                      const unsigned short* __restrict__ colb,
                      const unsigned short* __restrict__ hb,
                      float* __restrict__ y) {
    int wave = (int)((blockIdx.x * (unsigned)blockDim.x + threadIdx.x) >> 6);
    if (wave >= N_NODES) return;
    int lane = threadIdx.x & 63;
    int g = lane >> 3;   // group 0..7
    int l = lane & 7;    // covers feats [l*8, l*8+8)
    int r = wave;
    int4 c4 = *(const int4*)(cnt + (r << 4));
    int cn = c4.x + c4.y + c4.z + c4.w;
    const unsigned short* cb = colb + (size_t)r * KCAP;
    float acc[8];
#pragma unroll
    for (int i = 0; i < 8; ++i) acc[i] = 0.f;

    int j = g;
    for (; j + 24 < cn; j += 32) {
        int c0 = cb[j], c1 = cb[j + 8], c2 = cb[j + 16], c3 = cb[j + 24];
        uint4 q0 = ((const uint4*)(hb + (size_t)c0 * 64))[l];
        uint4 q1 = ((const uint4*)(hb + (size_t)c1 * 64))[l];
        uint4 q2 = ((const uint4*)(hb + (size_t)c2 * 64))[l];
        uint4 q3 = ((const uint4*)(hb + (size_t)c3 * 64))[l];
        acc8(acc, q0); acc8(acc, q1); acc8(acc, q2); acc8(acc, q3);
    }
    for (; j + 8 < cn; j += 16) {
        int c0 = cb[j];
        int c1 = cb[j + 8];
        uint4 q0 = ((const uint4*)(hb + (size_t)c0 * 64))[l];
        uint4 q1 = ((const uint4*)(hb + (size_t)c1 * 64))[l];
        acc8(acc, q0); acc8(acc, q1);
    }
    if (j < cn) {
        int c0 = cb[j];
        uint4 q0 = ((const uint4*)(hb + (size_t)c0 * 64))[l];
        acc8(acc, q0);
    }
    if (g == 0) {  // self term
        uint4 q = ((const uint4*)(hb + (size_t)r * 64))[l];
        acc8(acc, q);
    }
#pragma unroll
    for (int i = 0; i < 8; ++i) {
        acc[i] += __shfl_xor(acc[i], 8);
        acc[i] += __shfl_xor(acc[i], 16);
        acc[i] += __shfl_xor(acc[i], 32);
    }
    if (g == 0) {
        float dr = rsqrtf((float)cn + 1.0f);
        float4 o0 = make_float4(dr * acc[0], dr * acc[1], dr * acc[2], dr * acc[3]);
        float4 o1 = make_float4(dr * acc[4], dr * acc[5], dr * acc[6], dr * acc[7]);
        *(float4*)(y + (size_t)r * 64 + l * 8)     = o0;
        *(float4*)(y + (size_t)r * 64 + l * 8 + 4) = o1;
    }
}

// ---------------- launch ----------------

extern "C" void kernel_launch(void* const* d_in, const int* in_sizes, int n_in,
                              void* d_out, int out_size, void* d_ws, size_t ws_size,
                              hipStream_t stream) {
    const float* x  = (const float*)d_in[0];
    const float* W0 = (const float*)d_in[1];
    const float* W1 = (const float*)d_in[2];
    const int* edge = (const int*)d_in[3];
    const int E = in_sizes[3] / 2;
    const int N = N_NODES;
    const int* src = edge;
    const int* dst = edge + E;

    int nblkA = (E + EPB - 1) / EPB;          // 782 for E=800000
    if (nblkA > NBLKA_MAX) nblkA = NBLKA_MAX; // structural cap (E fixed by problem)

    auto align256 = [](size_t v) { return (v + 255) & ~(size_t)255; };
    char* ws = (char*)d_ws;
    size_t off = 0;
    int* cnt = (int*)(ws + off);       off += align256((size_t)N * CSTRIDE * 4);   // 3.2 MB
    int* cntA = (int*)(ws + off);      off += align256((size_t)NBKT * NBLKA_MAX * 4);   // 0.8 MB
    unsigned int* bktPairs = (unsigned int*)(ws + off);
    off += align256((size_t)NBKT * NBLKA_MAX * PCAP * 4);                          // 26.2 MB
    unsigned short* colb_d = (unsigned short*)(ws + off);
    off += align256((size_t)N * KCAP * 2);                                         // 9.6 MB (dense sorted)
    unsigned short* xb16 = (unsigned short*)(ws + off);
    off += align256((size_t)N * 128 * 2);                                          // 12.8 MB
    unsigned short* b16 = (unsigned short*)(ws + off);
    off += align256((size_t)N * 64 * 2);                                           // 6.4 MB
    unsigned short* W0t = (unsigned short*)(ws + off); off += align256(128 * 128 * 2);
    unsigned short* W1t = (unsigned short*)(ws + off); off += align256(64 * 128 * 2);
    // total ~59 MB

    float* out = (float*)d_out;

    // prep: transpose/cast weights
    prep<<<(3072 + 255) / 256, 256, 0, stream>>>(W0, W1, W0t, W1t);

    // build phase A: deterministic pair binning (no global atomics)
    bin_pairs<<<nblkA, 256, 0, stream>>>(src, dst, bktPairs, cntA, E, nblkA);

    // build phase B: single-writer dense window-sorted CSR (no global atomics)
    // R20: 1024-thread blocks — occ 8.7% -> ~50%
    build_sorted<<<NBKT, TB_B, 0, stream>>>(bktPairs, cntA, cnt, colb_d, nblkA);

    // x -> bf16, pre-scaled by rsqrt(deg)
    long n4 = (long)N * 32;
    convert_scale_bf16<<<(int)((n4 + 255) / 256), 256, 0, stream>>>(x, cnt, xb16);

    // fused: gather y1 tile -> MFMA MLP -> b16 (R6 structure, sorted dense list)
    gather_mlp<<<NPAD / 64, 256, 0, stream>>>(cnt, colb_d, xb16, W0t, W1t, b16);

    // layer 2 gather: out = Â b16 (R6 structure, sorted dense list)
    const int spmm_blocks = (N * 64 + 255) / 256;
    gather_spmm64_bf<<<spmm_blocks, 256, 0, stream>>>(cnt, colb_d, b16, out);
}

// Round 19
// 211.781 us; speedup vs baseline: 1.7353x; 1.0013x over previous
//
#include <hip/hip_runtime.h>
#include <hip/hip_bf16.h>

#define N_NODES 50000
#define NPAD 50048    // 782 blocks x 64 rows for the fused gather+MLP (R6 structure)
#define KCAP 96       // dense per-row capacity; P(deg > 96 | mean 32) ~ 1e-15
#define CSTRIDE 16    // 16 ints per row: 8 window counters live in ONE 64B line
#define NW 8          // R21: column windows 4->8; 1.6MB xb slices, 2 fit per XCD L2
#define CWIN 6250     // columns per window
#define NBKT 256      // row buckets in build; one block per bucket in phase B
#define RPB 196       // rows per bucket (196*256 = 50176 >= N)
#define PCAP 32       // pair slots per (bucket, phase-A block); Binomial(2048,1/256) mean 8, 32~11sigma
#define EPB 1024      // edges per phase-A block
#define NBLKA_MAX 800 // cap for lcnt LDS array (E<=819200)
#define TB_B 1024     // phase-B block size (R20-verified: occ 8.7%->ok, build left top-5)

typedef short v8s __attribute__((ext_vector_type(8)));
typedef unsigned short v8us __attribute__((ext_vector_type(8)));
typedef float v4f __attribute__((ext_vector_type(4)));

// ---------------- helpers ----------------

__device__ __forceinline__ unsigned short f2bf_rne(float f) {
    unsigned int u = __float_as_uint(f);
    u += 0x7FFF + ((u >> 16) & 1);      // round-to-nearest-even
    return (unsigned short)(u >> 16);
}
__device__ __forceinline__ float bflo(unsigned int u) {
    return __uint_as_float(u << 16);
}
__device__ __forceinline__ float bfhi(unsigned int u) {
    return __uint_as_float(u & 0xffff0000u);
}
__device__ __forceinline__ unsigned int pk(float lo, float hi) {
    return (unsigned int)f2bf_rne(lo) | ((unsigned int)f2bf_rne(hi) << 16);
}
__device__ __forceinline__ void acc8(float* acc, uint4 q) {
    acc[0] += bflo(q.x); acc[1] += bfhi(q.x);
    acc[2] += bflo(q.y); acc[3] += bfhi(q.y);
    acc[4] += bflo(q.z); acc[5] += bfhi(q.z);
    acc[6] += bflo(q.w); acc[7] += bfhi(q.w);
}
__device__ __forceinline__ int deg8(const int* cnt, int r) {
    int4 a = *(const int4*)(cnt + ((size_t)r << 4));
    int4 b = *(const int4*)(cnt + ((size_t)r << 4) + 4);
    return a.x + a.y + a.z + a.w + b.x + b.y + b.z + b.w;
}

// ---------------- prep: transpose/cast weights only ----------------
// W0t[n][k] = bf16(W0[k][n]) (128x128); W1t[n][k] = bf16(W1[k][n]) (64x128)
__global__ void prep(const float* __restrict__ W0, const float* __restrict__ W1,
                     unsigned short* __restrict__ W0t, unsigned short* __restrict__ W1t) {
    int j = blockIdx.x * blockDim.x + threadIdx.x;
    if (j < 2048) {
        int n = j >> 4, kc = j & 15;
        unsigned short tmp[8];
#pragma unroll
        for (int q = 0; q < 8; ++q) tmp[q] = f2bf_rne(W0[(kc * 8 + q) * 128 + n]);
        *(uint4*)(W0t + (size_t)n * 128 + kc * 8) = *(uint4*)tmp;
    } else if (j < 3072) {
        int jj = j - 2048;
        int n = jj >> 4, kc = jj & 15;
        unsigned short tmp[8];
#pragma unroll
        for (int q = 0; q < 8; ++q) tmp[q] = f2bf_rne(W1[(kc * 8 + q) * 64 + n]);
        *(uint4*)(W1t + (size_t)n * 128 + kc * 8) = *(uint4*)tmp;
    }
}

// ---------------- build phase A: deterministic pair binning, ZERO global atomics ----
// R19 (verified R17: build WRITE 73->6.3 MB): the ~70 MB write tax was the 1.6M
// device-scope atomicAdds (memory-side line RMW for cross-XCD visibility).
// Block i owns slot range (bucket, i): deterministic placement, LDS staging.
__global__ void bin_pairs(const int* __restrict__ src, const int* __restrict__ dst,
                          unsigned int* __restrict__ bktPairs, int* __restrict__ cntA,
                          int nEdges, int nblkA) {
    __shared__ unsigned int stage[NBKT * PCAP];   // 32 KB
    __shared__ int scnt[NBKT];
    int tid = threadIdx.x;
    for (int i = tid; i < NBKT; i += 256) scnt[i] = 0;
    __syncthreads();
    int e0 = blockIdx.x * EPB;
#pragma unroll
    for (int k = 0; k < EPB / 256; ++k) {
        int e = e0 + k * 256 + tid;
        if (e < nEdges) {
            int s = src[e], d = dst[e];
            int bs = s / RPB, bd = d / RPB;
            int p = atomicAdd(&scnt[bs], 1);                    // LDS atomic (cheap)
            if (p < PCAP) stage[bs * PCAP + p] = ((unsigned int)s << 16) | (unsigned int)d;
            p = atomicAdd(&scnt[bd], 1);
            if (p < PCAP) stage[bd * PCAP + p] = ((unsigned int)d << 16) | (unsigned int)s;
        }
    }
    __syncthreads();
    // flush: thread t owns bucket t
    int n = scnt[tid]; if (n > PCAP) n = PCAP;
    unsigned int* dp = bktPairs + ((size_t)tid * nblkA + blockIdx.x) * PCAP;
    for (int j = 0; j < n; ++j) dp[j] = stage[tid * PCAP + j];
    cntA[(size_t)tid * nblkA + blockIdx.x] = n;
}

// ---------------- build phase B: single-writer dense window-sorted CSR --------
// One block (1024 thr, R20) per bucket: LDS histogram of (row, colwindow) ->
// per-row dense prefix -> LDS-offset scatter. ZERO global atomics; colb_d dense
// and window-sorted. R21: NW=8 histogram (RPB*8 = 6.3KB LDS); cnt = 8 counts/row.
__global__ __launch_bounds__(TB_B, 1)
void build_sorted(const unsigned int* __restrict__ bktPairs,
                  const int* __restrict__ cntA,
                  int* __restrict__ cnt, unsigned short* __restrict__ colb_d,
                  int nblkA) {
    __shared__ int hist[RPB * NW];    // counts, then running dense positions
    __shared__ int lcnt[NBLKA_MAX];
    int tid = threadIdx.x;
    int k = blockIdx.x;
    int lo = k * RPB;
    for (int i = tid; i < nblkA; i += TB_B) lcnt[i] = cntA[(size_t)k * nblkA + i];
    for (int i = tid; i < RPB * NW; i += TB_B) hist[i] = 0;
    __syncthreads();
    const unsigned int* bp = bktPairs + (size_t)k * nblkA * PCAP;
    int nslots = nblkA * PCAP;
    // pass 1: histogram (coalesced slot stream)
    for (int s = tid; s < nslots; s += TB_B) {
        int blk = s >> 5, j = s & (PCAP - 1);
        if (j < lcnt[blk]) {
            unsigned int pr = bp[s];
            int rr = (int)(pr >> 16) - lo;
            int c = (int)(pr & 0xFFFFu);
            atomicAdd(&hist[rr * NW + c / CWIN], 1);
        }
    }
    __syncthreads();
    // per-row: store cnt (8 ints), convert hist to dense window prefix
    for (int rr = tid; rr < RPB; rr += TB_B) {
        int r = lo + rr;
        if (r < N_NODES) {
            int h[NW];
#pragma unroll
            for (int j = 0; j < NW; ++j) h[j] = hist[rr * NW + j];
            *(int4*)(cnt + ((size_t)r << 4))     = make_int4(h[0], h[1], h[2], h[3]);
            *(int4*)(cnt + ((size_t)r << 4) + 4) = make_int4(h[4], h[5], h[6], h[7]);
            int p = 0;
#pragma unroll
            for (int j = 0; j < NW; ++j) { int t = h[j]; hist[rr * NW + j] = p; p += t; }
        }
    }
    __syncthreads();
    // pass 2: scatter into dense window-sorted list
    for (int s = tid; s < nslots; s += TB_B) {
        int blk = s >> 5, j = s & (PCAP - 1);
        if (j < lcnt[blk]) {
            unsigned int pr = bp[s];
            int rr = (int)(pr >> 16) - lo;
            int c = (int)(pr & 0xFFFFu);
            int pos = atomicAdd(&hist[rr * NW + c / CWIN], 1);
            if (pos < KCAP) colb_d[(size_t)(lo + rr) * KCAP + pos] = (unsigned short)c;
        }
    }
}

// ---------------- bf16 conversion (pre-scaled by rsqrt(deg)) ----------------

__global__ void convert_scale_bf16(const float* __restrict__ x, const int* __restrict__ cnt,
                                   unsigned short* __restrict__ xb) {
    long i = (long)blockIdx.x * blockDim.x + threadIdx.x;
    if (i >= (long)N_NODES * 32) return;
    int r = (int)(i >> 5);
    float s = rsqrtf((float)deg8(cnt, r) + 1.0f);
    float4 v = ((const float4*)x)[i];
    ushort4 o;
    o.x = f2bf_rne(v.x * s); o.y = f2bf_rne(v.y * s);
    o.z = f2bf_rne(v.z * s); o.w = f2bf_rne(v.w * s);
    ((ushort4*)xb)[i] = o;
}

// ---------------- fused gather(F=128) + MFMA MLP -----------------------------
// EXACT R6 loop structure (71 us best: occ (256,4), 4 rows/group-iter, 8-deep
// pipelined loop) on the dense window-sorted list (R21: NW=8 sort granularity).
// R18 counters: time = FETCH / ~2.2 TB/s (fill-rate regime); 147 MB vs 102 MB
// per-XCD compulsory -> 45 MB band-desync overage; 1.6MB slices (2 fit in L2)
// tolerate one-window drift. A-frag m120; C/D m89. No __syncthreads (R12).
__global__ __launch_bounds__(256, 4)
void gather_mlp(const int* __restrict__ cnt,
                const unsigned short* __restrict__ colb,
                const unsigned short* __restrict__ xb,
                const unsigned short* __restrict__ W0t,
                const unsigned short* __restrict__ W1t,
                unsigned short* __restrict__ b16) {
    __shared__ __align__(16) unsigned short Al[4][16 * 136];  // gathered y1 tiles
    __shared__ __align__(16) unsigned short Hl[4][16 * 136];  // hidden tiles
    int t = threadIdx.x;
    int w = t >> 6, lane = t & 63;
    int g = lane >> 4, l = lane & 15;      // group / lane-in-group
    int tilebase = blockIdx.x * 64 + w * 16;
    unsigned short* A = &Al[w][0];
    unsigned short* H = &Hl[w][0];

    // ---- gather phase: group g handles rows tilebase + g + {0,4,8,12}
#pragma unroll
    for (int it = 0; it < 4; ++it) {
        int rr = g + it * 4;
        int r = tilebase + rr;
        float acc[8];
#pragma unroll
        for (int i = 0; i < 8; ++i) acc[i] = 0.f;
        float dr = 0.f;
        if (r < N_NODES) {
            int cn = deg8(cnt, r);
            const unsigned short* cb = colb + (size_t)r * KCAP;
            int j = 0;
            // 8-deep: one ushort8 index load, 8 dwordx4 row loads in flight
            for (; j + 7 < cn; j += 8) {
                v8us ci = *(const v8us*)(cb + j);
                uint4 q[8];
#pragma unroll
                for (int u = 0; u < 8; ++u)
                    q[u] = ((const uint4*)(xb + (size_t)ci[u] * 128))[l];
#pragma unroll
                for (int u = 0; u < 8; ++u) acc8(acc, q[u]);
            }
            // 4-deep tail
            for (; j + 3 < cn; j += 4) {
                int c0 = cb[j], c1 = cb[j + 1], c2 = cb[j + 2], c3 = cb[j + 3];
                uint4 q0 = ((const uint4*)(xb + (size_t)c0 * 128))[l];
                uint4 q1 = ((const uint4*)(xb + (size_t)c1 * 128))[l];
                uint4 q2 = ((const uint4*)(xb + (size_t)c2 * 128))[l];
                uint4 q3 = ((const uint4*)(xb + (size_t)c3 * 128))[l];
                acc8(acc, q0); acc8(acc, q1); acc8(acc, q2); acc8(acc, q3);
            }
            for (; j < cn; ++j) {
                int c0 = cb[j];
                uint4 q0 = ((const uint4*)(xb + (size_t)c0 * 128))[l];
                acc8(acc, q0);
            }
            // self term
            uint4 qs = ((const uint4*)(xb + (size_t)r * 128))[l];
            acc8(acc, qs);
            dr = rsqrtf((float)cn + 1.0f);
        }
        uint4 o;
        o.x = pk(dr * acc[0], dr * acc[1]);
        o.y = pk(dr * acc[2], dr * acc[3]);
        o.z = pk(dr * acc[4], dr * acc[5]);
        o.w = pk(dr * acc[6], dr * acc[7]);
        *(uint4*)(A + rr * 136 + l * 8) = o;
    }

    // ---- MLP phase (per-wave 16-row tile) ----
    int quad = g, lm = l;
    v8s af[4];
#pragma unroll
    for (int ks = 0; ks < 4; ++ks)
        af[ks] = *(const v8s*)(A + lm * 136 + ks * 32 + quad * 8);

    // phase 1: H(16x128) = relu(A @ W0)
#pragma unroll
    for (int n0 = 0; n0 < 8; ++n0) {
        v4f acc = {0.f, 0.f, 0.f, 0.f};
        const unsigned short* wrow = W0t + (size_t)(n0 * 16 + lm) * 128 + quad * 8;
#pragma unroll
        for (int ks = 0; ks < 4; ++ks) {
            v8s bf = *(const v8s*)(wrow + ks * 32);
            acc = __builtin_amdgcn_mfma_f32_16x16x32_bf16(af[ks], bf, acc, 0, 0, 0);
        }
#pragma unroll
        for (int i = 0; i < 4; ++i)
            H[(quad * 4 + i) * 136 + n0 * 16 + lm] = f2bf_rne(fmaxf(acc[i], 0.f));
    }

    // phase 2: b(16x64) = H @ W1, scale by rsqrt(deg), store bf16
    v8s hf[4];
#pragma unroll
    for (int ks = 0; ks < 4; ++ks)
        hf[ks] = *(const v8s*)(H + lm * 136 + ks * 32 + quad * 8);
    float sc[4];
#pragma unroll
    for (int i = 0; i < 4; ++i) {
        int r = tilebase + quad * 4 + i;
        sc[i] = (r < N_NODES) ? rsqrtf((float)deg8(cnt, r) + 1.0f) : 0.f;
    }
#pragma unroll
    for (int n0 = 0; n0 < 4; ++n0) {
        v4f acc = {0.f, 0.f, 0.f, 0.f};
        const unsigned short* wrow = W1t + (size_t)(n0 * 16 + lm) * 128 + quad * 8;
#pragma unroll
        for (int ks = 0; ks < 4; ++ks) {
            v8s bf = *(const v8s*)(wrow + ks * 32);
            acc = __builtin_amdgcn_mfma_f32_16x16x32_bf16(hf[ks], bf, acc, 0, 0, 0);
        }
#pragma unroll
        for (int i = 0; i < 4; ++i) {
            int r = tilebase + quad * 4 + i;
            if (r < N_NODES)
                b16[(size_t)r * 64 + n0 * 16 + lm] = f2bf_rne(acc[i] * sc[i]);
        }
    }
}

// ---------------- gather SpMM, F=64, bf16 pre-scaled input ----------------
// EXACT R6 structure (occ (256,4), 4-deep) on the dense window-sorted list.
__global__ __launch_bounds__(256, 4)
void gather_spmm64_bf(const int* __restrict__ cnt,
                      const unsigned short* __restrict__ colb,
                      const unsigned short* __restrict__ hb,
                      float* __restrict__ y) {
    int wave = (int)((blockIdx.x * (unsigned)blockDim.x + threadIdx.x) >> 6);
    if (wave >= N_NODES) return;
    int lane = threadIdx.x & 63;
    int g = lane >> 3;   // group 0..7
    int l = lane & 7;    // covers feats [l*8, l*8+8)
    int r = wave;
    int cn = deg8(cnt, r);
    const unsigned short* cb = colb + (size_t)r * KCAP;
    float acc[8];
#pragma unroll
    for (int i = 0; i < 8; ++i) acc[i] = 0.f;

    int j = g;
    for (; j + 24 < cn; j += 32) {
        int c0 = cb[j], c1 = cb[j + 8], c2 = cb[j + 16], c3 = cb[j + 24];
        uint4 q0 = ((const uint4*)(hb + (size_t)c0 * 64))[l];
        uint4 q1 = ((const uint4*)(hb + (size_t)c1 * 64))[l];
        uint4 q2 = ((const uint4*)(hb + (size_t)c2 * 64))[l];
        uint4 q3 = ((const uint4*)(hb + (size_t)c3 * 64))[l];
        acc8(acc, q0); acc8(acc, q1); acc8(acc, q2); acc8(acc, q3);
    }
    for (; j + 8 < cn; j += 16) {
        int c0 = cb[j];
        int c1 = cb[j + 8];
        uint4 q0 = ((const uint4*)(hb + (size_t)c0 * 64))[l];
        uint4 q1 = ((const uint4*)(hb + (size_t)c1 * 64))[l];
        acc8(acc, q0); acc8(acc, q1);
    }
    if (j < cn) {
        int c0 = cb[j];
        uint4 q0 = ((const uint4*)(hb + (size_t)c0 * 64))[l];
        acc8(acc, q0);
    }
    if (g == 0) {  // self term
        uint4 q = ((const uint4*)(hb + (size_t)r * 64))[l];
        acc8(acc, q);
    }
#pragma unroll
    for (int i = 0; i < 8; ++i) {
        acc[i] += __shfl_xor(acc[i], 8);
        acc[i] += __shfl_xor(acc[i], 16);
        acc[i] += __shfl_xor(acc[i], 32);
    }
    if (g == 0) {
        float dr = rsqrtf((float)cn + 1.0f);
        float4 o0 = make_float4(dr * acc[0], dr * acc[1], dr * acc[2], dr * acc[3]);
        float4 o1 = make_float4(dr * acc[4], dr * acc[5], dr * acc[6], dr * acc[7]);
        *(float4*)(y + (size_t)r * 64 + l * 8)     = o0;
        *(float4*)(y + (size_t)r * 64 + l * 8 + 4) = o1;
    }
}

// ---------------- launch ----------------

extern "C" void kernel_launch(void* const* d_in, const int* in_sizes, int n_in,
                              void* d_out, int out_size, void* d_ws, size_t ws_size,
                              hipStream_t stream) {
    const float* x  = (const float*)d_in[0];
    const float* W0 = (const float*)d_in[1];
    const float* W1 = (const float*)d_in[2];
    const int* edge = (const int*)d_in[3];
    const int E = in_sizes[3] / 2;
    const int N = N_NODES;
    const int* src = edge;
    const int* dst = edge + E;

    int nblkA = (E + EPB - 1) / EPB;          // 782 for E=800000
    if (nblkA > NBLKA_MAX) nblkA = NBLKA_MAX; // structural cap (E fixed by problem)

    auto align256 = [](size_t v) { return (v + 255) & ~(size_t)255; };
    char* ws = (char*)d_ws;
    size_t off = 0;
    int* cnt = (int*)(ws + off);       off += align256((size_t)N * CSTRIDE * 4);   // 3.2 MB
    int* cntA = (int*)(ws + off);      off += align256((size_t)NBKT * NBLKA_MAX * 4);   // 0.8 MB
    unsigned int* bktPairs = (unsigned int*)(ws + off);
    off += align256((size_t)NBKT * NBLKA_MAX * PCAP * 4);                          // 26.2 MB
    unsigned short* colb_d = (unsigned short*)(ws + off);
    off += align256((size_t)N * KCAP * 2);                                         // 9.6 MB (dense sorted)
    unsigned short* xb16 = (unsigned short*)(ws + off);
    off += align256((size_t)N * 128 * 2);                                          // 12.8 MB
    unsigned short* b16 = (unsigned short*)(ws + off);
    off += align256((size_t)N * 64 * 2);                                           // 6.4 MB
    unsigned short* W0t = (unsigned short*)(ws + off); off += align256(128 * 128 * 2);
    unsigned short* W1t = (unsigned short*)(ws + off); off += align256(64 * 128 * 2);
    // total ~59 MB

    float* out = (float*)d_out;

    // prep: transpose/cast weights
    prep<<<(3072 + 255) / 256, 256, 0, stream>>>(W0, W1, W0t, W1t);

    // build phase A: deterministic pair binning (no global atomics)
    bin_pairs<<<nblkA, 256, 0, stream>>>(src, dst, bktPairs, cntA, E, nblkA);

    // build phase B: single-writer dense window-sorted CSR (no global atomics)
    build_sorted<<<NBKT, TB_B, 0, stream>>>(bktPairs, cntA, cnt, colb_d, nblkA);

    // x -> bf16, pre-scaled by rsqrt(deg)
    long n4 = (long)N * 32;
    convert_scale_bf16<<<(int)((n4 + 255) / 256), 256, 0, stream>>>(x, cnt, xb16);

    // fused: gather y1 tile -> MFMA MLP -> b16 (R6 structure, NW=8 sorted list)
    gather_mlp<<<NPAD / 64, 256, 0, stream>>>(cnt, colb_d, xb16, W0t, W1t, b16);

    // layer 2 gather: out = Â b16 (R6 structure, NW=8 sorted list)
    const int spmm_blocks = (N * 64 + 255) / 256;
    gather_spmm64_bf<<<spmm_blocks, 256, 0, stream>>>(cnt, colb_d, b16, out);
}

// Round 20
// 211.058 us; speedup vs baseline: 1.7412x; 1.0034x over previous
//
#include <hip/hip_runtime.h>
#include <hip/hip_bf16.h>

#define N_NODES 50000
#define NPAD 50048    // 782 blocks x 64 rows for the fused gather+MLP (R6 structure)
#define KCAP 96       // dense per-row capacity; P(deg > 96 | mean 32) ~ 1e-15
#define CSTRIDE 16    // 16 ints per row: 8 window counters live in ONE 64B line
#define NW 8          // column windows (R21: null vs NW=4, kept — no cost)
#define CWIN 6250     // columns per window
#define NBKT 256      // row buckets in build; one block per bucket in phase B
#define RPB 196       // rows per bucket (196*256 = 50176 >= N)
#define PCAP 32       // pair slots per (bucket, phase-A block); Binomial(2048,1/256) mean 8, 32~11sigma
#define EPB 1024      // edges per phase-A block
#define NBLKA_MAX 800 // cap for lcnt LDS array (E<=819200)
#define TB_B 1024     // phase-B block size (R20-verified: build left top-5)

typedef short v8s __attribute__((ext_vector_type(8)));
typedef unsigned short v8us __attribute__((ext_vector_type(8)));
typedef float v4f __attribute__((ext_vector_type(4)));

// ---------------- helpers ----------------

__device__ __forceinline__ unsigned short f2bf_rne(float f) {
    unsigned int u = __float_as_uint(f);
    u += 0x7FFF + ((u >> 16) & 1);      // round-to-nearest-even
    return (unsigned short)(u >> 16);
}
__device__ __forceinline__ float bflo(unsigned int u) {
    return __uint_as_float(u << 16);
}
__device__ __forceinline__ float bfhi(unsigned int u) {
    return __uint_as_float(u & 0xffff0000u);
}
__device__ __forceinline__ unsigned int pk(float lo, float hi) {
    return (unsigned int)f2bf_rne(lo) | ((unsigned int)f2bf_rne(hi) << 16);
}
__device__ __forceinline__ void acc8(float* acc, uint4 q) {
    acc[0] += bflo(q.x); acc[1] += bfhi(q.x);
    acc[2] += bflo(q.y); acc[3] += bfhi(q.y);
    acc[4] += bflo(q.z); acc[5] += bfhi(q.z);
    acc[6] += bflo(q.w); acc[7] += bfhi(q.w);
}
__device__ __forceinline__ int deg8(const int* cnt, int r) {
    int4 a = *(const int4*)(cnt + ((size_t)r << 4));
    int4 b = *(const int4*)(cnt + ((size_t)r << 4) + 4);
    return a.x + a.y + a.z + a.w + b.x + b.y + b.z + b.w;
}

// ---------------- prep: transpose/cast weights only ----------------
// W0t[n][k] = bf16(W0[k][n]) (128x128); W1t[n][k] = bf16(W1[k][n]) (64x128)
__global__ void prep(const float* __restrict__ W0, const float* __restrict__ W1,
                     unsigned short* __restrict__ W0t, unsigned short* __restrict__ W1t) {
    int j = blockIdx.x * blockDim.x + threadIdx.x;
    if (j < 2048) {
        int n = j >> 4, kc = j & 15;
        unsigned short tmp[8];
#pragma unroll
        for (int q = 0; q < 8; ++q) tmp[q] = f2bf_rne(W0[(kc * 8 + q) * 128 + n]);
        *(uint4*)(W0t + (size_t)n * 128 + kc * 8) = *(uint4*)tmp;
    } else if (j < 3072) {
        int jj = j - 2048;
        int n = jj >> 4, kc = jj & 15;
        unsigned short tmp[8];
#pragma unroll
        for (int q = 0; q < 8; ++q) tmp[q] = f2bf_rne(W1[(kc * 8 + q) * 64 + n]);
        *(uint4*)(W1t + (size_t)n * 128 + kc * 8) = *(uint4*)tmp;
    }
}

// ---------------- build phase A: deterministic pair binning, ZERO global atomics ----
// R19 (verified R17: build WRITE 73->6.3 MB): the ~70 MB write tax was the 1.6M
// device-scope atomicAdds (memory-side line RMW for cross-XCD visibility).
// Block i owns slot range (bucket, i): deterministic placement, LDS staging.
__global__ void bin_pairs(const int* __restrict__ src, const int* __restrict__ dst,
                          unsigned int* __restrict__ bktPairs, int* __restrict__ cntA,
                          int nEdges, int nblkA) {
    __shared__ unsigned int stage[NBKT * PCAP];   // 32 KB
    __shared__ int scnt[NBKT];
    int tid = threadIdx.x;
    for (int i = tid; i < NBKT; i += 256) scnt[i] = 0;
    __syncthreads();
    int e0 = blockIdx.x * EPB;
#pragma unroll
    for (int k = 0; k < EPB / 256; ++k) {
        int e = e0 + k * 256 + tid;
        if (e < nEdges) {
            int s = src[e], d = dst[e];
            int bs = s / RPB, bd = d / RPB;
            int p = atomicAdd(&scnt[bs], 1);                    // LDS atomic (cheap)
            if (p < PCAP) stage[bs * PCAP + p] = ((unsigned int)s << 16) | (unsigned int)d;
            p = atomicAdd(&scnt[bd], 1);
            if (p < PCAP) stage[bd * PCAP + p] = ((unsigned int)d << 16) | (unsigned int)s;
        }
    }
    __syncthreads();
    // flush: thread t owns bucket t
    int n = scnt[tid]; if (n > PCAP) n = PCAP;
    unsigned int* dp = bktPairs + ((size_t)tid * nblkA + blockIdx.x) * PCAP;
    for (int j = 0; j < n; ++j) dp[j] = stage[tid * PCAP + j];
    cntA[(size_t)tid * nblkA + blockIdx.x] = n;
}

// ---------------- build phase B: single-writer dense window-sorted CSR --------
// One block (1024 thr, R20) per bucket: LDS histogram of (row, colwindow) ->
// per-row dense prefix -> LDS-offset scatter. ZERO global atomics; colb_d dense
// and window-sorted. NW=8 histogram (RPB*8 = 6.3KB LDS); cnt = 8 counts/row.
__global__ __launch_bounds__(TB_B, 1)
void build_sorted(const unsigned int* __restrict__ bktPairs,
                  const int* __restrict__ cntA,
                  int* __restrict__ cnt, unsigned short* __restrict__ colb_d,
                  int nblkA) {
    __shared__ int hist[RPB * NW];    // counts, then running dense positions
    __shared__ int lcnt[NBLKA_MAX];
    int tid = threadIdx.x;
    int k = blockIdx.x;
    int lo = k * RPB;
    for (int i = tid; i < nblkA; i += TB_B) lcnt[i] = cntA[(size_t)k * nblkA + i];
    for (int i = tid; i < RPB * NW; i += TB_B) hist[i] = 0;
    __syncthreads();
    const unsigned int* bp = bktPairs + (size_t)k * nblkA * PCAP;
    int nslots = nblkA * PCAP;
    // pass 1: histogram (coalesced slot stream)
    for (int s = tid; s < nslots; s += TB_B) {
        int blk = s >> 5, j = s & (PCAP - 1);
        if (j < lcnt[blk]) {
            unsigned int pr = bp[s];
            int rr = (int)(pr >> 16) - lo;
            int c = (int)(pr & 0xFFFFu);
            atomicAdd(&hist[rr * NW + c / CWIN], 1);
        }
    }
    __syncthreads();
    // per-row: store cnt (8 ints), convert hist to dense window prefix
    for (int rr = tid; rr < RPB; rr += TB_B) {
        int r = lo + rr;
        if (r < N_NODES) {
            int h[NW];
#pragma unroll
            for (int j = 0; j < NW; ++j) h[j] = hist[rr * NW + j];
            *(int4*)(cnt + ((size_t)r << 4))     = make_int4(h[0], h[1], h[2], h[3]);
            *(int4*)(cnt + ((size_t)r << 4) + 4) = make_int4(h[4], h[5], h[6], h[7]);
            int p = 0;
#pragma unroll
            for (int j = 0; j < NW; ++j) { int t = h[j]; hist[rr * NW + j] = p; p += t; }
        }
    }
    __syncthreads();
    // pass 2: scatter into dense window-sorted list
    for (int s = tid; s < nslots; s += TB_B) {
        int blk = s >> 5, j = s & (PCAP - 1);
        if (j < lcnt[blk]) {
            unsigned int pr = bp[s];
            int rr = (int)(pr >> 16) - lo;
            int c = (int)(pr & 0xFFFFu);
            int pos = atomicAdd(&hist[rr * NW + c / CWIN], 1);
            if (pos < KCAP) colb_d[(size_t)(lo + rr) * KCAP + pos] = (unsigned short)c;
        }
    }
}

// ---------------- bf16 conversion (pre-scaled by rsqrt(deg)) ----------------

__global__ void convert_scale_bf16(const float* __restrict__ x, const int* __restrict__ cnt,
                                   unsigned short* __restrict__ xb) {
    long i = (long)blockIdx.x * blockDim.x + threadIdx.x;
    if (i >= (long)N_NODES * 32) return;
    int r = (int)(i >> 5);
    float s = rsqrtf((float)deg8(cnt, r) + 1.0f);
    float4 v = ((const float4*)x)[i];
    ushort4 o;
    o.x = f2bf_rne(v.x * s); o.y = f2bf_rne(v.y * s);
    o.z = f2bf_rne(v.z * s); o.w = f2bf_rne(v.w * s);
    ((ushort4*)xb)[i] = o;
}

// ---------------- fused gather(F=128) + MFMA MLP -----------------------------
// UNCHANGED in R22 (regression tripwire). Measured regime: time = FETCH/2.2TB/s,
// FETCH pinned ~147 MB vs 102 MB per-XCD compulsory (R9/R17/R21 locality nulls).
// A-frag m120; C/D m89. No __syncthreads (R12 pattern).
__global__ __launch_bounds__(256, 4)
void gather_mlp(const int* __restrict__ cnt,
                const unsigned short* __restrict__ colb,
                const unsigned short* __restrict__ xb,
                const unsigned short* __restrict__ W0t,
                const unsigned short* __restrict__ W1t,
                unsigned short* __restrict__ b16) {
    __shared__ __align__(16) unsigned short Al[4][16 * 136];  // gathered y1 tiles
    __shared__ __align__(16) unsigned short Hl[4][16 * 136];  // hidden tiles
    int t = threadIdx.x;
    int w = t >> 6, lane = t & 63;
    int g = lane >> 4, l = lane & 15;      // group / lane-in-group
    int tilebase = blockIdx.x * 64 + w * 16;
    unsigned short* A = &Al[w][0];
    unsigned short* H = &Hl[w][0];

    // ---- gather phase: group g handles rows tilebase + g + {0,4,8,12}
#pragma unroll
    for (int it = 0; it < 4; ++it) {
        int rr = g + it * 4;
        int r = tilebase + rr;
        float acc[8];
#pragma unroll
        for (int i = 0; i < 8; ++i) acc[i] = 0.f;
        float dr = 0.f;
        if (r < N_NODES) {
            int cn = deg8(cnt, r);
            const unsigned short* cb = colb + (size_t)r * KCAP;
            int j = 0;
            // 8-deep: one ushort8 index load, 8 dwordx4 row loads in flight
            for (; j + 7 < cn; j += 8) {
                v8us ci = *(const v8us*)(cb + j);
                uint4 q[8];
#pragma unroll
                for (int u = 0; u < 8; ++u)
                    q[u] = ((const uint4*)(xb + (size_t)ci[u] * 128))[l];
#pragma unroll
                for (int u = 0; u < 8; ++u) acc8(acc, q[u]);
            }
            // 4-deep tail
            for (; j + 3 < cn; j += 4) {
                int c0 = cb[j], c1 = cb[j + 1], c2 = cb[j + 2], c3 = cb[j + 3];
                uint4 q0 = ((const uint4*)(xb + (size_t)c0 * 128))[l];
                uint4 q1 = ((const uint4*)(xb + (size_t)c1 * 128))[l];
                uint4 q2 = ((const uint4*)(xb + (size_t)c2 * 128))[l];
                uint4 q3 = ((const uint4*)(xb + (size_t)c3 * 128))[l];
                acc8(acc, q0); acc8(acc, q1); acc8(acc, q2); acc8(acc, q3);
            }
            for (; j < cn; ++j) {
                int c0 = cb[j];
                uint4 q0 = ((const uint4*)(xb + (size_t)c0 * 128))[l];
                acc8(acc, q0);
            }
            // self term
            uint4 qs = ((const uint4*)(xb + (size_t)r * 128))[l];
            acc8(acc, qs);
            dr = rsqrtf((float)cn + 1.0f);
        }
        uint4 o;
        o.x = pk(dr * acc[0], dr * acc[1]);
        o.y = pk(dr * acc[2], dr * acc[3]);
        o.z = pk(dr * acc[4], dr * acc[5]);
        o.w = pk(dr * acc[6], dr * acc[7]);
        *(uint4*)(A + rr * 136 + l * 8) = o;
    }

    // ---- MLP phase (per-wave 16-row tile) ----
    int quad = g, lm = l;
    v8s af[4];
#pragma unroll
    for (int ks = 0; ks < 4; ++ks)
        af[ks] = *(const v8s*)(A + lm * 136 + ks * 32 + quad * 8);

    // phase 1: H(16x128) = relu(A @ W0)
#pragma unroll
    for (int n0 = 0; n0 < 8; ++n0) {
        v4f acc = {0.f, 0.f, 0.f, 0.f};
        const unsigned short* wrow = W0t + (size_t)(n0 * 16 + lm) * 128 + quad * 8;
#pragma unroll
        for (int ks = 0; ks < 4; ++ks) {
            v8s bf = *(const v8s*)(wrow + ks * 32);
            acc = __builtin_amdgcn_mfma_f32_16x16x32_bf16(af[ks], bf, acc, 0, 0, 0);
        }
#pragma unroll
        for (int i = 0; i < 4; ++i)
            H[(quad * 4 + i) * 136 + n0 * 16 + lm] = f2bf_rne(fmaxf(acc[i], 0.f));
    }

    // phase 2: b(16x64) = H @ W1, scale by rsqrt(deg), store bf16
    v8s hf[4];
#pragma unroll
    for (int ks = 0; ks < 4; ++ks)
        hf[ks] = *(const v8s*)(H + lm * 136 + ks * 32 + quad * 8);
    float sc[4];
#pragma unroll
    for (int i = 0; i < 4; ++i) {
        int r = tilebase + quad * 4 + i;
        sc[i] = (r < N_NODES) ? rsqrtf((float)deg8(cnt, r) + 1.0f) : 0.f;
    }
#pragma unroll
    for (int n0 = 0; n0 < 4; ++n0) {
        v4f acc = {0.f, 0.f, 0.f, 0.f};
        const unsigned short* wrow = W1t + (size_t)(n0 * 16 + lm) * 128 + quad * 8;
#pragma unroll
        for (int ks = 0; ks < 4; ++ks) {
            v8s bf = *(const v8s*)(wrow + ks * 32);
            acc = __builtin_amdgcn_mfma_f32_16x16x32_bf16(hf[ks], bf, acc, 0, 0, 0);
        }
#pragma unroll
        for (int i = 0; i < 4; ++i) {
            int r = tilebase + quad * 4 + i;
            if (r < N_NODES)
                b16[(size_t)r * 64 + n0 * 16 + lm] = f2bf_rne(acc[i] * sc[i]);
        }
    }
}

// ---------------- gather SpMM, F=64, bf16 pre-scaled input ----------------
// R22: restructured to gather_mlp's PROVEN 8-deep shape. Old: wave/row, 8 groups
// x 8 lanes, ~4 neighbors/group -> 4-deep loop engages once, mostly 1-2-deep
// (the pre-R6 shallow-pipeline signature; never measured, est. hidden 50-65 us).
// New: 2 rows/wave, 4 groups x 8 lanes per row, stride-4 walk, 8-deep main loop
// (engages at deg>=31+g ~ always at mean deg 33): per-lane 8x16B in flight.
// Reduce: shfl_xor 8,16 within the 32-lane half (never crosses rows).
__global__ __launch_bounds__(256, 4)
void gather_spmm64_bf(const int* __restrict__ cnt,
                      const unsigned short* __restrict__ colb,
                      const unsigned short* __restrict__ hb,
                      float* __restrict__ y) {
    int wave = (int)((blockIdx.x * (unsigned)blockDim.x + threadIdx.x) >> 6);
    int lane = threadIdx.x & 63;
    int half = lane >> 5;          // row-in-wave 0/1
    int hl = lane & 31;
    int g = hl >> 3;               // group 0..3 (stride-4 neighbor walk)
    int l = hl & 7;                // covers feats [l*8, l*8+8)
    int r = wave * 2 + half;
    if (r >= N_NODES) return;
    int cn = deg8(cnt, r);
    const unsigned short* cb = colb + (size_t)r * KCAP;
    float acc[8];
#pragma unroll
    for (int i = 0; i < 8; ++i) acc[i] = 0.f;

    int j = g;
    // 8-deep main: neighbors j, j+4, ..., j+28 (engages when cn > j+28)
    for (; j + 28 < cn; j += 32) {
        uint4 q[8];
#pragma unroll
        for (int u = 0; u < 8; ++u) {
            int c = cb[j + u * 4];
            q[u] = ((const uint4*)(hb + (size_t)c * 64))[l];
        }
#pragma unroll
        for (int u = 0; u < 8; ++u) acc8(acc, q[u]);
    }
    // 4-deep tail
    for (; j + 12 < cn; j += 16) {
        int c0 = cb[j], c1 = cb[j + 4], c2 = cb[j + 8], c3 = cb[j + 12];
        uint4 q0 = ((const uint4*)(hb + (size_t)c0 * 64))[l];
        uint4 q1 = ((const uint4*)(hb + (size_t)c1 * 64))[l];
        uint4 q2 = ((const uint4*)(hb + (size_t)c2 * 64))[l];
        uint4 q3 = ((const uint4*)(hb + (size_t)c3 * 64))[l];
        acc8(acc, q0); acc8(acc, q1); acc8(acc, q2); acc8(acc, q3);
    }
    for (; j < cn; j += 4) {
        int c0 = cb[j];
        uint4 q0 = ((const uint4*)(hb + (size_t)c0 * 64))[l];
        acc8(acc, q0);
    }
    if (g == 0) {  // self term (once per row)
        uint4 q = ((const uint4*)(hb + (size_t)r * 64))[l];
        acc8(acc, q);
    }
#pragma unroll
    for (int i = 0; i < 8; ++i) {
        acc[i] += __shfl_xor(acc[i], 8);
        acc[i] += __shfl_xor(acc[i], 16);
    }
    if (g == 0) {
        float dr = rsqrtf((float)cn + 1.0f);
        float4 o0 = make_float4(dr * acc[0], dr * acc[1], dr * acc[2], dr * acc[3]);
        float4 o1 = make_float4(dr * acc[4], dr * acc[5], dr * acc[6], dr * acc[7]);
        *(float4*)(y + (size_t)r * 64 + l * 8)     = o0;
        *(float4*)(y + (size_t)r * 64 + l * 8 + 4) = o1;
    }
}

// ---------------- launch ----------------

extern "C" void kernel_launch(void* const* d_in, const int* in_sizes, int n_in,
                              void* d_out, int out_size, void* d_ws, size_t ws_size,
                              hipStream_t stream) {
    const float* x  = (const float*)d_in[0];
    const float* W0 = (const float*)d_in[1];
    const float* W1 = (const float*)d_in[2];
    const int* edge = (const int*)d_in[3];
    const int E = in_sizes[3] / 2;
    const int N = N_NODES;
    const int* src = edge;
    const int* dst = edge + E;

    int nblkA = (E + EPB - 1) / EPB;          // 782 for E=800000
    if (nblkA > NBLKA_MAX) nblkA = NBLKA_MAX; // structural cap (E fixed by problem)

    auto align256 = [](size_t v) { return (v + 255) & ~(size_t)255; };
    char* ws = (char*)d_ws;
    size_t off = 0;
    int* cnt = (int*)(ws + off);       off += align256((size_t)N * CSTRIDE * 4);   // 3.2 MB
    int* cntA = (int*)(ws + off);      off += align256((size_t)NBKT * NBLKA_MAX * 4);   // 0.8 MB
    unsigned int* bktPairs = (unsigned int*)(ws + off);
    off += align256((size_t)NBKT * NBLKA_MAX * PCAP * 4);                          // 26.2 MB
    unsigned short* colb_d = (unsigned short*)(ws + off);
    off += align256((size_t)N * KCAP * 2);                                         // 9.6 MB (dense sorted)
    unsigned short* xb16 = (unsigned short*)(ws + off);
    off += align256((size_t)N * 128 * 2);                                          // 12.8 MB
    unsigned short* b16 = (unsigned short*)(ws + off);
    off += align256((size_t)N * 64 * 2);                                           // 6.4 MB
    unsigned short* W0t = (unsigned short*)(ws + off); off += align256(128 * 128 * 2);
    unsigned short* W1t = (unsigned short*)(ws + off); off += align256(64 * 128 * 2);
    // total ~59 MB

    float* out = (float*)d_out;

    // prep: transpose/cast weights
    prep<<<(3072 + 255) / 256, 256, 0, stream>>>(W0, W1, W0t, W1t);

    // build phase A: deterministic pair binning (no global atomics)
    bin_pairs<<<nblkA, 256, 0, stream>>>(src, dst, bktPairs, cntA, E, nblkA);

    // build phase B: single-writer dense window-sorted CSR (no global atomics)
    build_sorted<<<NBKT, TB_B, 0, stream>>>(bktPairs, cntA, cnt, colb_d, nblkA);

    // x -> bf16, pre-scaled by rsqrt(deg)
    long n4 = (long)N * 32;
    convert_scale_bf16<<<(int)((n4 + 255) / 256), 256, 0, stream>>>(x, cnt, xb16);

    // fused: gather y1 tile -> MFMA MLP -> b16 (R6 structure, sorted list)
    gather_mlp<<<NPAD / 64, 256, 0, stream>>>(cnt, colb_d, xb16, W0t, W1t, b16);

    // layer 2 gather: out = Â b16 (R22: 2 rows/wave, 8-deep pipeline)
    const int waves2 = (N + 1) / 2;
    const int spmm_blocks = (waves2 * 64 + 255) / 256;
    gather_spmm64_bf<<<spmm_blocks, 256, 0, stream>>>(cnt, colb_d, b16, out);
}

// Round 21
// 202.271 us; speedup vs baseline: 1.8169x; 1.0434x over previous
//
#include <hip/hip_runtime.h>
#include <hip/hip_bf16.h>

#define N_NODES 50000
#define NPAD 50048    // 782 blocks x 64 rows for the fused gather+MLP (R6 structure)
#define KCAP 96       // dense per-row capacity; P(deg > 96 | mean 32) ~ 1e-15
#define CSTRIDE 16    // 16 ints per row: 8 window counters live in ONE 64B line
#define NW 8          // column windows (R21: null vs NW=4, kept — no cost)
#define CWIN 6250     // columns per window
#define NBKT 256      // row buckets in build; one block per bucket in phase B
#define RPB 196       // rows per bucket (196*256 = 50176 >= N)
#define PCAP 32       // pair slots per (bucket, phase-A block); Binomial(2048,1/256) mean 8, 32~11sigma
#define EPB 1024      // edges per phase-A block
#define NBLKA_MAX 800 // cap for lcnt LDS array (E<=819200)
#define TB_B 1024     // phase-B block size (R20: 16 waves/CU)

typedef short v8s __attribute__((ext_vector_type(8)));
typedef unsigned short v8us __attribute__((ext_vector_type(8)));
typedef float v4f __attribute__((ext_vector_type(4)));

// ---------------- helpers ----------------

__device__ __forceinline__ unsigned short f2bf_rne(float f) {
    unsigned int u = __float_as_uint(f);
    u += 0x7FFF + ((u >> 16) & 1);      // round-to-nearest-even
    return (unsigned short)(u >> 16);
}
__device__ __forceinline__ float bflo(unsigned int u) {
    return __uint_as_float(u << 16);
}
__device__ __forceinline__ float bfhi(unsigned int u) {
    return __uint_as_float(u & 0xffff0000u);
}
__device__ __forceinline__ unsigned int pk(float lo, float hi) {
    return (unsigned int)f2bf_rne(lo) | ((unsigned int)f2bf_rne(hi) << 16);
}
__device__ __forceinline__ void acc8(float* acc, uint4 q) {
    acc[0] += bflo(q.x); acc[1] += bfhi(q.x);
    acc[2] += bflo(q.y); acc[3] += bfhi(q.y);
    acc[4] += bflo(q.z); acc[5] += bfhi(q.z);
    acc[6] += bflo(q.w); acc[7] += bfhi(q.w);
}
__device__ __forceinline__ int deg8(const int* cnt, int r) {
    int4 a = *(const int4*)(cnt + ((size_t)r << 4));
    int4 b = *(const int4*)(cnt + ((size_t)r << 4) + 4);
    return a.x + a.y + a.z + a.w + b.x + b.y + b.z + b.w;
}

// ---------------- prep: transpose/cast weights only ----------------
// W0t[n][k] = bf16(W0[k][n]) (128x128); W1t[n][k] = bf16(W1[k][n]) (64x128)
__global__ void prep(const float* __restrict__ W0, const float* __restrict__ W1,
                     unsigned short* __restrict__ W0t, unsigned short* __restrict__ W1t) {
    int j = blockIdx.x * blockDim.x + threadIdx.x;
    if (j < 2048) {
        int n = j >> 4, kc = j & 15;
        unsigned short tmp[8];
#pragma unroll
        for (int q = 0; q < 8; ++q) tmp[q] = f2bf_rne(W0[(kc * 8 + q) * 128 + n]);
        *(uint4*)(W0t + (size_t)n * 128 + kc * 8) = *(uint4*)tmp;
    } else if (j < 3072) {
        int jj = j - 2048;
        int n = jj >> 4, kc = jj & 15;
        unsigned short tmp[8];
#pragma unroll
        for (int q = 0; q < 8; ++q) tmp[q] = f2bf_rne(W1[(kc * 8 + q) * 64 + n]);
        *(uint4*)(W1t + (size_t)n * 128 + kc * 8) = *(uint4*)tmp;
    }
}

// ---------------- build phase A: deterministic pair binning, ZERO global atomics ----
// R19 (verified R17: build WRITE 73->6.3 MB): the ~70 MB write tax was the 1.6M
// device-scope atomicAdds (memory-side line RMW for cross-XCD visibility).
// Block i owns slot range (bucket, i): deterministic placement, LDS staging.
__global__ void bin_pairs(const int* __restrict__ src, const int* __restrict__ dst,
                          unsigned int* __restrict__ bktPairs, int* __restrict__ cntA,
                          int nEdges, int nblkA) {
    __shared__ unsigned int stage[NBKT * PCAP];   // 32 KB
    __shared__ int scnt[NBKT];
    int tid = threadIdx.x;
    for (int i = tid; i < NBKT; i += 256) scnt[i] = 0;
    __syncthreads();
    int e0 = blockIdx.x * EPB;
#pragma unroll
    for (int k = 0; k < EPB / 256; ++k) {
        int e = e0 + k * 256 + tid;
        if (e < nEdges) {
            int s = src[e], d = dst[e];
            int bs = s / RPB, bd = d / RPB;
            int p = atomicAdd(&scnt[bs], 1);                    // LDS atomic (cheap)
            if (p < PCAP) stage[bs * PCAP + p] = ((unsigned int)s << 16) | (unsigned int)d;
            p = atomicAdd(&scnt[bd], 1);
            if (p < PCAP) stage[bd * PCAP + p] = ((unsigned int)d << 16) | (unsigned int)s;
        }
    }
    __syncthreads();
    // flush: thread t owns bucket t
    int n = scnt[tid]; if (n > PCAP) n = PCAP;
    unsigned int* dp = bktPairs + ((size_t)tid * nblkA + blockIdx.x) * PCAP;
    for (int j = 0; j < n; ++j) dp[j] = stage[tid * PCAP + j];
    cntA[(size_t)tid * nblkA + blockIdx.x] = n;
}

// ---------------- build phase B: single-writer dense window-sorted CSR --------
// One block (1024 thr) per bucket: LDS histogram of (row, colwindow) -> per-row
// dense prefix -> LDS-offset scatter. ZERO global atomics; colb_d dense+sorted.
// R23: slot stream vectorized — uint4 load covers 4 slots, 4x fewer iterations,
// fully-empty groups early-continue with zero traffic. (R17 @4 waves was 85 us
// issue/latency-bound on 2x25600 scalar gated loads; R20 @16 waves unverified,
// suspected largest invisible sink at ~40-60 us of the 139 us residual.)
__global__ __launch_bounds__(TB_B, 1)
void build_sorted(const unsigned int* __restrict__ bktPairs,
                  const int* __restrict__ cntA,
                  int* __restrict__ cnt, unsigned short* __restrict__ colb_d,
                  int nblkA) {
    __shared__ int hist[RPB * NW];    // counts, then running dense positions
    __shared__ int lcnt[NBLKA_MAX];
    int tid = threadIdx.x;
    int k = blockIdx.x;
    int lo = k * RPB;
    for (int i = tid; i < nblkA; i += TB_B) lcnt[i] = cntA[(size_t)k * nblkA + i];
    for (int i = tid; i < RPB * NW; i += TB_B) hist[i] = 0;
    __syncthreads();
    const unsigned int* bp = bktPairs + (size_t)k * nblkA * PCAP;
    int ngroups = nblkA * (PCAP / 4);      // uint4 groups of 4 slots
    // pass 1: histogram (vectorized slot stream)
    for (int s4 = tid; s4 < ngroups; s4 += TB_B) {
        int blk = s4 >> 3;                 // 8 groups per 32-slot chunk
        int v = lcnt[blk] - ((s4 & 7) << 2);
        if (v <= 0) continue;
        uint4 pq = ((const uint4*)bp)[s4];
        if (v > 4) v = 4;
        unsigned int pr[4] = {pq.x, pq.y, pq.z, pq.w};
#pragma unroll
        for (int u = 0; u < 4; ++u) {
            if (u < v) {
                int rr = (int)(pr[u] >> 16) - lo;
                int c = (int)(pr[u] & 0xFFFFu);
                atomicAdd(&hist[rr * NW + c / CWIN], 1);
            }
        }
    }
    __syncthreads();
    // per-row: store cnt (8 ints), convert hist to dense window prefix
    for (int rr = tid; rr < RPB; rr += TB_B) {
        int r = lo + rr;
        if (r < N_NODES) {
            int h[NW];
#pragma unroll
            for (int j = 0; j < NW; ++j) h[j] = hist[rr * NW + j];
            *(int4*)(cnt + ((size_t)r << 4))     = make_int4(h[0], h[1], h[2], h[3]);
            *(int4*)(cnt + ((size_t)r << 4) + 4) = make_int4(h[4], h[5], h[6], h[7]);
            int p = 0;
#pragma unroll
            for (int j = 0; j < NW; ++j) { int t = h[j]; hist[rr * NW + j] = p; p += t; }
        }
    }
    __syncthreads();
    // pass 2: scatter into dense window-sorted list (vectorized)
    for (int s4 = tid; s4 < ngroups; s4 += TB_B) {
        int blk = s4 >> 3;
        int v = lcnt[blk] - ((s4 & 7) << 2);
        if (v <= 0) continue;
        uint4 pq = ((const uint4*)bp)[s4];
        if (v > 4) v = 4;
        unsigned int pr[4] = {pq.x, pq.y, pq.z, pq.w};
#pragma unroll
        for (int u = 0; u < 4; ++u) {
            if (u < v) {
                int rr = (int)(pr[u] >> 16) - lo;
                int c = (int)(pr[u] & 0xFFFFu);
                int pos = atomicAdd(&hist[rr * NW + c / CWIN], 1);
                if (pos < KCAP) colb_d[(size_t)(lo + rr) * KCAP + pos] = (unsigned short)c;
            }
        }
    }
}

// ---------------- bf16 conversion (pre-scaled by rsqrt(deg)) ----------------

__global__ void convert_scale_bf16(const float* __restrict__ x, const int* __restrict__ cnt,
                                   unsigned short* __restrict__ xb) {
    long i = (long)blockIdx.x * blockDim.x + threadIdx.x;
    if (i >= (long)N_NODES * 32) return;
    int r = (int)(i >> 5);
    float s = rsqrtf((float)deg8(cnt, r) + 1.0f);
    float4 v = ((const float4*)x)[i];
    ushort4 o;
    o.x = f2bf_rne(v.x * s); o.y = f2bf_rne(v.y * s);
    o.z = f2bf_rne(v.z * s); o.w = f2bf_rne(v.w * s);
    ((ushort4*)xb)[i] = o;
}

// ---------------- fused gather(F=128) + MFMA MLP -----------------------------
// UNCHANGED (regression tripwire: ~72 us, FETCH ~146 MB, time = FETCH/2.2TB/s;
// R9/R17/R21 locality nulls pin FETCH at 1.43x the 102 MB per-XCD compulsory).
// A-frag m120; C/D m89. No __syncthreads (R12 pattern).
__global__ __launch_bounds__(256, 4)
void gather_mlp(const int* __restrict__ cnt,
                const unsigned short* __restrict__ colb,
                const unsigned short* __restrict__ xb,
                const unsigned short* __restrict__ W0t,
                const unsigned short* __restrict__ W1t,
                unsigned short* __restrict__ b16) {
    __shared__ __align__(16) unsigned short Al[4][16 * 136];  // gathered y1 tiles
    __shared__ __align__(16) unsigned short Hl[4][16 * 136];  // hidden tiles
    int t = threadIdx.x;
    int w = t >> 6, lane = t & 63;
    int g = lane >> 4, l = lane & 15;      // group / lane-in-group
    int tilebase = blockIdx.x * 64 + w * 16;
    unsigned short* A = &Al[w][0];
    unsigned short* H = &Hl[w][0];

    // ---- gather phase: group g handles rows tilebase + g + {0,4,8,12}
#pragma unroll
    for (int it = 0; it < 4; ++it) {
        int rr = g + it * 4;
        int r = tilebase + rr;
        float acc[8];
#pragma unroll
        for (int i = 0; i < 8; ++i) acc[i] = 0.f;
        float dr = 0.f;
        if (r < N_NODES) {
            int cn = deg8(cnt, r);
            const unsigned short* cb = colb + (size_t)r * KCAP;
            int j = 0;
            // 8-deep: one ushort8 index load, 8 dwordx4 row loads in flight
            for (; j + 7 < cn; j += 8) {
                v8us ci = *(const v8us*)(cb + j);
                uint4 q[8];
#pragma unroll
                for (int u = 0; u < 8; ++u)
                    q[u] = ((const uint4*)(xb + (size_t)ci[u] * 128))[l];
#pragma unroll
                for (int u = 0; u < 8; ++u) acc8(acc, q[u]);
            }
            // 4-deep tail
            for (; j + 3 < cn; j += 4) {
                int c0 = cb[j], c1 = cb[j + 1], c2 = cb[j + 2], c3 = cb[j + 3];
                uint4 q0 = ((const uint4*)(xb + (size_t)c0 * 128))[l];
                uint4 q1 = ((const uint4*)(xb + (size_t)c1 * 128))[l];
                uint4 q2 = ((const uint4*)(xb + (size_t)c2 * 128))[l];
                uint4 q3 = ((const uint4*)(xb + (size_t)c3 * 128))[l];
                acc8(acc, q0); acc8(acc, q1); acc8(acc, q2); acc8(acc, q3);
            }
            for (; j < cn; ++j) {
                int c0 = cb[j];
                uint4 q0 = ((const uint4*)(xb + (size_t)c0 * 128))[l];
                acc8(acc, q0);
            }
            // self term
            uint4 qs = ((const uint4*)(xb + (size_t)r * 128))[l];
            acc8(acc, qs);
            dr = rsqrtf((float)cn + 1.0f);
        }
        uint4 o;
        o.x = pk(dr * acc[0], dr * acc[1]);
        o.y = pk(dr * acc[2], dr * acc[3]);
        o.z = pk(dr * acc[4], dr * acc[5]);
        o.w = pk(dr * acc[6], dr * acc[7]);
        *(uint4*)(A + rr * 136 + l * 8) = o;
    }

    // ---- MLP phase (per-wave 16-row tile) ----
    int quad = g, lm = l;
    v8s af[4];
#pragma unroll
    for (int ks = 0; ks < 4; ++ks)
        af[ks] = *(const v8s*)(A + lm * 136 + ks * 32 + quad * 8);

    // phase 1: H(16x128) = relu(A @ W0)
#pragma unroll
    for (int n0 = 0; n0 < 8; ++n0) {
        v4f acc = {0.f, 0.f, 0.f, 0.f};
        const unsigned short* wrow = W0t + (size_t)(n0 * 16 + lm) * 128 + quad * 8;
#pragma unroll
        for (int ks = 0; ks < 4; ++ks) {
            v8s bf = *(const v8s*)(wrow + ks * 32);
            acc = __builtin_amdgcn_mfma_f32_16x16x32_bf16(af[ks], bf, acc, 0, 0, 0);
        }
#pragma unroll
        for (int i = 0; i < 4; ++i)
            H[(quad * 4 + i) * 136 + n0 * 16 + lm] = f2bf_rne(fmaxf(acc[i], 0.f));
    }

    // phase 2: b(16x64) = H @ W1, scale by rsqrt(deg), store bf16
    v8s hf[4];
#pragma unroll
    for (int ks = 0; ks < 4; ++ks)
        hf[ks] = *(const v8s*)(H + lm * 136 + ks * 32 + quad * 8);
    float sc[4];
#pragma unroll
    for (int i = 0; i < 4; ++i) {
        int r = tilebase + quad * 4 + i;
        sc[i] = (r < N_NODES) ? rsqrtf((float)deg8(cnt, r) + 1.0f) : 0.f;
    }
#pragma unroll
    for (int n0 = 0; n0 < 4; ++n0) {
        v4f acc = {0.f, 0.f, 0.f, 0.f};
        const unsigned short* wrow = W1t + (size_t)(n0 * 16 + lm) * 128 + quad * 8;
#pragma unroll
        for (int ks = 0; ks < 4; ++ks) {
            v8s bf = *(const v8s*)(wrow + ks * 32);
            acc = __builtin_amdgcn_mfma_f32_16x16x32_bf16(hf[ks], bf, acc, 0, 0, 0);
        }
#pragma unroll
        for (int i = 0; i < 4; ++i) {
            int r = tilebase + quad * 4 + i;
            if (r < N_NODES)
                b16[(size_t)r * 64 + n0 * 16 + lm] = f2bf_rne(acc[i] * sc[i]);
        }
    }
}

// ---------------- gather SpMM, F=64, bf16 pre-scaled input ----------------
// R22 structure kept (2 rows/wave, 8-deep pipeline; null on total but not
// harmful, structurally matched to gather_mlp's proven shape).
__global__ __launch_bounds__(256, 4)
void gather_spmm64_bf(const int* __restrict__ cnt,
                      const unsigned short* __restrict__ colb,
                      const unsigned short* __restrict__ hb,
                      float* __restrict__ y) {
    int wave = (int)((blockIdx.x * (unsigned)blockDim.x + threadIdx.x) >> 6);
    int lane = threadIdx.x & 63;
    int half = lane >> 5;          // row-in-wave 0/1
    int hl = lane & 31;
    int g = hl >> 3;               // group 0..3 (stride-4 neighbor walk)
    int l = hl & 7;                // covers feats [l*8, l*8+8)
    int r = wave * 2 + half;
    if (r >= N_NODES) return;
    int cn = deg8(cnt, r);
    const unsigned short* cb = colb + (size_t)r * KCAP;
    float acc[8];
#pragma unroll
    for (int i = 0; i < 8; ++i) acc[i] = 0.f;

    int j = g;
    // 8-deep main: neighbors j, j+4, ..., j+28 (engages when cn > j+28)
    for (; j + 28 < cn; j += 32) {
        uint4 q[8];
#pragma unroll
        for (int u = 0; u < 8; ++u) {
            int c = cb[j + u * 4];
            q[u] = ((const uint4*)(hb + (size_t)c * 64))[l];
        }
#pragma unroll
        for (int u = 0; u < 8; ++u) acc8(acc, q[u]);
    }
    // 4-deep tail
    for (; j + 12 < cn; j += 16) {
        int c0 = cb[j], c1 = cb[j + 4], c2 = cb[j + 8], c3 = cb[j + 12];
        uint4 q0 = ((const uint4*)(hb + (size_t)c0 * 64))[l];
        uint4 q1 = ((const uint4*)(hb + (size_t)c1 * 64))[l];
        uint4 q2 = ((const uint4*)(hb + (size_t)c2 * 64))[l];
        uint4 q3 = ((const uint4*)(hb + (size_t)c3 * 64))[l];
        acc8(acc, q0); acc8(acc, q1); acc8(acc, q2); acc8(acc, q3);
    }
    for (; j < cn; j += 4) {
        int c0 = cb[j];
        uint4 q0 = ((const uint4*)(hb + (size_t)c0 * 64))[l];
        acc8(acc, q0);
    }
    if (g == 0) {  // self term (once per row)
        uint4 q = ((const uint4*)(hb + (size_t)r * 64))[l];
        acc8(acc, q);
    }
#pragma unroll
    for (int i = 0; i < 8; ++i) {
        acc[i] += __shfl_xor(acc[i], 8);
        acc[i] += __shfl_xor(acc[i], 16);
    }
    if (g == 0) {
        float dr = rsqrtf((float)cn + 1.0f);
        float4 o0 = make_float4(dr * acc[0], dr * acc[1], dr * acc[2], dr * acc[3]);
        float4 o1 = make_float4(dr * acc[4], dr * acc[5], dr * acc[6], dr * acc[7]);
        *(float4*)(y + (size_t)r * 64 + l * 8)     = o0;
        *(float4*)(y + (size_t)r * 64 + l * 8 + 4) = o1;
    }
}

// ---------------- launch ----------------

extern "C" void kernel_launch(void* const* d_in, const int* in_sizes, int n_in,
                              void* d_out, int out_size, void* d_ws, size_t ws_size,
                              hipStream_t stream) {
    const float* x  = (const float*)d_in[0];
    const float* W0 = (const float*)d_in[1];
    const float* W1 = (const float*)d_in[2];
    const int* edge = (const int*)d_in[3];
    const int E = in_sizes[3] / 2;
    const int N = N_NODES;
    const int* src = edge;
    const int* dst = edge + E;

    int nblkA = (E + EPB - 1) / EPB;          // 782 for E=800000
    if (nblkA > NBLKA_MAX) nblkA = NBLKA_MAX; // structural cap (E fixed by problem)

    auto align256 = [](size_t v) { return (v + 255) & ~(size_t)255; };
    char* ws = (char*)d_ws;
    size_t off = 0;
    int* cnt = (int*)(ws + off);       off += align256((size_t)N * CSTRIDE * 4);   // 3.2 MB
    int* cntA = (int*)(ws + off);      off += align256((size_t)NBKT * NBLKA_MAX * 4);   // 0.8 MB
    unsigned int* bktPairs = (unsigned int*)(ws + off);
    off += align256((size_t)NBKT * NBLKA_MAX * PCAP * 4);                          // 26.2 MB
    unsigned short* colb_d = (unsigned short*)(ws + off);
    off += align256((size_t)N * KCAP * 2);                                         // 9.6 MB (dense sorted)
    unsigned short* xb16 = (unsigned short*)(ws + off);
    off += align256((size_t)N * 128 * 2);                                          // 12.8 MB
    unsigned short* b16 = (unsigned short*)(ws + off);
    off += align256((size_t)N * 64 * 2);                                           // 6.4 MB
    unsigned short* W0t = (unsigned short*)(ws + off); off += align256(128 * 128 * 2);
    unsigned short* W1t = (unsigned short*)(ws + off); off += align256(64 * 128 * 2);
    // total ~59 MB

    float* out = (float*)d_out;

    // prep: transpose/cast weights
    prep<<<(3072 + 255) / 256, 256, 0, stream>>>(W0, W1, W0t, W1t);

    // build phase A: deterministic pair binning (no global atomics)
    bin_pairs<<<nblkA, 256, 0, stream>>>(src, dst, bktPairs, cntA, E, nblkA);

    // build phase B: single-writer dense window-sorted CSR (vectorized slot scan)
    build_sorted<<<NBKT, TB_B, 0, stream>>>(bktPairs, cntA, cnt, colb_d, nblkA);

    // x -> bf16, pre-scaled by rsqrt(deg)
    long n4 = (long)N * 32;
    convert_scale_bf16<<<(int)((n4 + 255) / 256), 256, 0, stream>>>(x, cnt, xb16);

    // fused: gather y1 tile -> MFMA MLP -> b16 (R6 structure, sorted list)
    gather_mlp<<<NPAD / 64, 256, 0, stream>>>(cnt, colb_d, xb16, W0t, W1t, b16);

    // layer 2 gather: out = Â b16 (2 rows/wave, 8-deep pipeline)
    const int waves2 = (N + 1) / 2;
    const int spmm_blocks = (waves2 * 64 + 255) / 256;
    gather_spmm64_bf<<<spmm_blocks, 256, 0, stream>>>(cnt, colb_d, b16, out);
}